// Round 4
// baseline (149.933 us; speedup 1.0000x reference)
//
#include <hip/hip_runtime.h>

// Head: x[8,2048,1024] fp32 -> q,k,v = x@w{q,k,v} -> causal softmax(q k^T * sqrt(128)) @ v
// Precision: bf16x3 split-GEMM for Q/K projections and QK^T (fp32-grade scores), bf16 V/PV.

#define NB 8
#define NT 2048
#define NE 1024
#define ND 128
#define NM (NB * NT)  // 16384

typedef unsigned short U16;
typedef unsigned int U32;
typedef __attribute__((ext_vector_type(8))) short vbf8;  // 8 bf16 (4 VGPR) MFMA frag
typedef __attribute__((ext_vector_type(4))) float vf4;   // MFMA 16x16 accum

__device__ __forceinline__ U16 f2bf(float f) {  // RNE fp32->bf16
  U32 u = __builtin_bit_cast(U32, f);
  u += 0x7fffu + ((u >> 16) & 1u);
  return (U16)(u >> 16);
}
__device__ __forceinline__ float bf2f(U16 h) {
  U32 u = ((U32)h) << 16;
  return __builtin_bit_cast(float, u);
}
__device__ __forceinline__ void gl_lds16(const void* g, void* l) {
  // async global->LDS, 16B per lane; LDS dest = wave-uniform base + lane*16
  __builtin_amdgcn_global_load_lds((__attribute__((address_space(1))) void*)g,
                                   (__attribute__((address_space(3))) void*)l, 16, 0, 0);
}

// ---------------- kernel 1: weight transpose + split (fold sqrt(128) into wq) ---------
__global__ void wsplit_kernel(const float* __restrict__ wq, const float* __restrict__ wk,
                              const float* __restrict__ wv, U16* __restrict__ wth,
                              U16* __restrict__ wtl) {
  int id = blockIdx.x * 256 + threadIdx.x;  // [0, 384*1024)
  if (id >= 384 * 1024) return;
  int n = id >> 10, e = id & 1023;
  float v;
  if (n < 128)      v = wq[e * 128 + n] * 11.313708498984761f;  // scores * d^0.5 folded in
  else if (n < 256) v = wk[e * 128 + (n - 128)];
  else              v = wv[e * 128 + (n - 256)];
  U16 h = f2bf(v);
  wth[id] = h;
  wtl[id] = f2bf(v - bf2f(h));
}

// ---------------- kernel 2: QKV projection, bf16x3 split GEMM ------------------------
// Tile 64(M)x128(N), BK=64. grid (256, 3): y 0->Q(hi/lo) 1->K(hi/lo) 2->V(bf16, vt).
// LDS layout [row][8 granules of 16B], granule XOR-swizzled by (row&7) on BOTH sides.
__global__ __launch_bounds__(256, 3) void qkv_kernel(
    const float* __restrict__ x, const U16* __restrict__ wth, const U16* __restrict__ wtl,
    U16* __restrict__ qh, U16* __restrict__ ql, U16* __restrict__ kh, U16* __restrict__ kl,
    U16* __restrict__ vt) {
  __shared__ __align__(16) char smem[49152];  // Ah/Al 8KB each, Bh/Bl 16KB each
  char* Ah = smem;
  char* Al = smem + 8192;
  char* Bh = smem + 16384;
  char* Bl = smem + 32768;

  const int tid = threadIdx.x;
  const int w = tid >> 6, lane = tid & 63;
  const int fr = lane & 15, fq = lane >> 4;
  const int m0 = blockIdx.x * 64;
  const int nt = blockIdx.y;
  const U16* bh_src = wth + nt * (128 * 1024);
  const U16* bl_src = wtl + nt * (128 * 1024);

  const vf4 vzero = {0.f, 0.f, 0.f, 0.f};
  vf4 acc[2][4];
#pragma unroll
  for (int i = 0; i < 2; ++i)
#pragma unroll
    for (int j = 0; j < 4; ++j) acc[i][j] = vzero;

  const int wm = (w >> 1) * 32, wn = (w & 1) * 64;  // wave tile 32x64
  const int arow = tid >> 2, ag = tid & 3;          // A stage: 2 granules (ag, ag+4)

  for (int k0 = 0; k0 < 1024; k0 += 64) {
    // --- async-stage B hi(/lo) [128 n][64 k], source-granule pre-swizzled ---
#pragma unroll
    for (int p = 0; p < 4; ++p) {
      const int g = p * 256 + tid;
      const int row = g >> 3, c = g & 7;
      const int sc = c ^ (row & 7);
      const int ldsb = (p * 256 + w * 64) * 16;  // wave-uniform granule base
      gl_lds16(bh_src + row * 1024 + k0 + sc * 8, Bh + ldsb);
      if (nt < 2) gl_lds16(bl_src + row * 1024 + k0 + sc * 8, Bl + ldsb);
    }
    // --- reg-stage + split A [64 m][64 k] from fp32 x, swizzled VALU stores ---
    {
      const float* s = x + (size_t)(m0 + arow) * 1024 + k0 + ag * 8;
      float v0[8], v1[8];
      ((float4*)v0)[0] = *(const float4*)(s);
      ((float4*)v0)[1] = *(const float4*)(s + 4);
      ((float4*)v1)[0] = *(const float4*)(s + 32);
      ((float4*)v1)[1] = *(const float4*)(s + 36);
      vbf8 h0, l0, h1, l1;
#pragma unroll
      for (int i = 0; i < 8; ++i) {
        U16 a = f2bf(v0[i]);
        h0[i] = (short)a; l0[i] = (short)f2bf(v0[i] - bf2f(a));
        U16 b = f2bf(v1[i]);
        h1[i] = (short)b; l1[i] = (short)f2bf(v1[i] - bf2f(b));
      }
      const int sw = arow & 7;
      *(vbf8*)(Ah + arow * 128 + ((ag ^ sw) << 4))       = h0;
      *(vbf8*)(Ah + arow * 128 + (((ag + 4) ^ sw) << 4)) = h1;
      if (nt < 2) {
        *(vbf8*)(Al + arow * 128 + ((ag ^ sw) << 4))       = l0;
        *(vbf8*)(Al + arow * 128 + (((ag + 4) ^ sw) << 4)) = l1;
      }
    }
    __syncthreads();

    if (nt < 2) {
#pragma unroll
      for (int kc = 0; kc < 2; ++kc) {
        vbf8 a_h[2], a_l[2], b_h[4], b_l[4];
#pragma unroll
        for (int i = 0; i < 2; ++i) {
          const int row = wm + i * 16 + fr;
          const int off = row * 128 + (((kc * 4 + fq) ^ (row & 7)) << 4);
          a_h[i] = *(const vbf8*)(Ah + off);
          a_l[i] = *(const vbf8*)(Al + off);
        }
#pragma unroll
        for (int j = 0; j < 4; ++j) {
          const int row = wn + j * 16 + fr;
          const int off = row * 128 + (((kc * 4 + fq) ^ (row & 7)) << 4);
          b_h[j] = *(const vbf8*)(Bh + off);
          b_l[j] = *(const vbf8*)(Bl + off);
        }
#pragma unroll
        for (int i = 0; i < 2; ++i)
#pragma unroll
          for (int j = 0; j < 4; ++j) {  // (Ah+Al)(Bh+Bl) dropping Al*Bl
            acc[i][j] = __builtin_amdgcn_mfma_f32_16x16x32_bf16(a_h[i], b_h[j], acc[i][j], 0, 0, 0);
            acc[i][j] = __builtin_amdgcn_mfma_f32_16x16x32_bf16(a_h[i], b_l[j], acc[i][j], 0, 0, 0);
            acc[i][j] = __builtin_amdgcn_mfma_f32_16x16x32_bf16(a_l[i], b_h[j], acc[i][j], 0, 0, 0);
          }
      }
    } else {  // V: hh only
#pragma unroll
      for (int kc = 0; kc < 2; ++kc) {
        vbf8 a_h[2], b_h[4];
#pragma unroll
        for (int i = 0; i < 2; ++i) {
          const int row = wm + i * 16 + fr;
          a_h[i] = *(const vbf8*)(Ah + row * 128 + (((kc * 4 + fq) ^ (row & 7)) << 4));
        }
#pragma unroll
        for (int j = 0; j < 4; ++j) {
          const int row = wn + j * 16 + fr;
          b_h[j] = *(const vbf8*)(Bh + row * 128 + (((kc * 4 + fq) ^ (row & 7)) << 4));
        }
#pragma unroll
        for (int i = 0; i < 2; ++i)
#pragma unroll
          for (int j = 0; j < 4; ++j)
            acc[i][j] = __builtin_amdgcn_mfma_f32_16x16x32_bf16(a_h[i], b_h[j], acc[i][j], 0, 0, 0);
      }
    }
    __syncthreads();
  }

  if (nt < 2) {  // Q or K: split hi/lo, natural [m][128] layout
    U16* dh = (nt == 0) ? qh : kh;
    U16* dl = (nt == 0) ? ql : kl;
#pragma unroll
    for (int i = 0; i < 2; ++i)
#pragma unroll
      for (int j = 0; j < 4; ++j)
#pragma unroll
        for (int r = 0; r < 4; ++r) {
          const int row = m0 + wm + i * 16 + fq * 4 + r;  // C/D: row=(lane>>4)*4+r
          const int col = wn + j * 16 + fr;               //      col=lane&15
          const float val = acc[i][j][r];
          const U16 h = f2bf(val);
          dh[row * 128 + col] = h;
          dl[row * 128 + col] = f2bf(val - bf2f(h));
        }
  } else {  // V: transpose via LDS -> vt[b][d][t], coalesced writeout
    U16* tl = (U16*)smem;  // [128 d][80] (pad kills conflicts; 20480 B < 48 KB)
#pragma unroll
    for (int i = 0; i < 2; ++i)
#pragma unroll
      for (int j = 0; j < 4; ++j)
#pragma unroll
        for (int r = 0; r < 4; ++r) {
          const int ml = wm + i * 16 + fq * 4 + r;
          const int col = wn + j * 16 + fr;
          tl[col * 80 + ml] = f2bf(acc[i][j][r]);
        }
    __syncthreads();
    const int bb = m0 >> 11, t0 = m0 & 2047;
#pragma unroll
    for (int p = 0; p < 4; ++p) {
      const int g = p * 256 + tid;
      const int d = g >> 3, c = g & 7;
      *(vbf8*)(vt + (size_t)(bb * 128 + d) * 2048 + t0 + c * 8) = *(const vbf8*)(tl + d * 80 + c * 8);
    }
  }
}

// ---------------- kernel 3: causal flash attention, direct-from-L2 -------------------
// 1024 blocks = 8 b x 128 q-groups of 16 rows. 4 waves per block s-split (t = w mod 4),
// zero LDS staging, zero in-loop barriers; K/V frags read straight from L2 (batch->XCD
// local). 4-way merge at the end. Group mapping {g,63-g,64+g,127-g} balances each CU.
__global__ __launch_bounds__(256, 4) void flash_kernel(
    const U16* __restrict__ qh, const U16* __restrict__ ql, const U16* __restrict__ kh,
    const U16* __restrict__ kl, const U16* __restrict__ vt, float* __restrict__ out) {
  __shared__ __align__(16) char smem[33280];
  // loop phase:  per-wave P buffer [16][72] U16 at smem + w*2304 (9216 B, aliases O_p)
  // merge phase: O_p [4][16][128] f32 (32768) | m_s [4][16] (256) | l_s [4][16] (256)

  const int tid = threadIdx.x;
  const int w = tid >> 6, lane = tid & 63;
  const int fr = lane & 15, fq = lane >> 4;
  const int bid = blockIdx.x;
  const int bb = bid & 7;            // batch == XCD (bid%8 round-robin) -> K/V L2-local
  const int j = bid >> 3;            // 0..127
  const int kk = j >> 5, gm = j & 31;
  const int g = (kk == 0) ? gm : (kk == 1) ? (63 - gm) : (kk == 2) ? (64 + gm) : (127 - gm);
  const int q0 = g * 16;

  // hoisted Q fragments (A-frag: row=lane&15, k=(lane>>4)*8 + kc*32)
  vbf8 q_h[4], q_l[4];
  {
    const int rg = (bb * 2048 + q0 + fr) * 128 + fq * 8;
#pragma unroll
    for (int kc = 0; kc < 4; ++kc) {
      q_h[kc] = *(const vbf8*)(qh + rg + kc * 32);
      q_l[kc] = *(const vbf8*)(ql + rg + kc * 32);
    }
  }

  // per-lane base pointers (B-frag: row=lane&15, k=(lane>>4)*8)
  const U16* kh_b = kh + (size_t)bb * 2048 * 128 + fr * 128 + fq * 8;
  const U16* kl_b = kl + (size_t)bb * 2048 * 128 + fr * 128 + fq * 8;
  const U16* vt_b = vt + (size_t)bb * 128 * 2048 + fr * 2048 + fq * 8;
  U16* pw = (U16*)(smem + w * 2304);  // [16][72]

  const vf4 vzero = {0.f, 0.f, 0.f, 0.f};
  vf4 oacc[8];
#pragma unroll
  for (int i = 0; i < 8; ++i) oacc[i] = vzero;
  float m_r[4], l_r[4];
#pragma unroll
  for (int r = 0; r < 4; ++r) { m_r[r] = -__builtin_inff(); l_r[r] = 0.f; }

  const int ntiles = (q0 + 79) >> 6;  // 64-wide s-tiles covering s <= q0+15
  for (int t = w; t < ntiles; t += 4) {
    const int s0 = t * 64;

    // S = Q K^T (bf16x3), K frags direct from global/L2
    vf4 sacc[4] = {vzero, vzero, vzero, vzero};
#pragma unroll
    for (int nf = 0; nf < 4; ++nf) {
      const U16* kh_t = kh_b + (s0 + nf * 16) * 128;
      const U16* kl_t = kl_b + (s0 + nf * 16) * 128;
#pragma unroll
      for (int kc = 0; kc < 4; ++kc) {
        const vbf8 kfh = *(const vbf8*)(kh_t + kc * 32);
        const vbf8 kfl = *(const vbf8*)(kl_t + kc * 32);
        sacc[nf] = __builtin_amdgcn_mfma_f32_16x16x32_bf16(q_h[kc], kfh, sacc[nf], 0, 0, 0);
        sacc[nf] = __builtin_amdgcn_mfma_f32_16x16x32_bf16(q_h[kc], kfl, sacc[nf], 0, 0, 0);
        sacc[nf] = __builtin_amdgcn_mfma_f32_16x16x32_bf16(q_l[kc], kfh, sacc[nf], 0, 0, 0);
      }
    }

    if (s0 + 63 > q0) {  // causal mask (diagonal tiles only)
#pragma unroll
      for (int nf = 0; nf < 4; ++nf) {
        const int s_g = s0 + nf * 16 + fr;
#pragma unroll
        for (int r = 0; r < 4; ++r) {
          const int q_g = q0 + fq * 4 + r;
          if (s_g > q_g) sacc[nf][r] = -__builtin_inff();
        }
      }
    }

    // online softmax; row-group = 16 consecutive lanes (same fq)
    float tmax[4];
#pragma unroll
    for (int r = 0; r < 4; ++r)
      tmax[r] = fmaxf(fmaxf(sacc[0][r], sacc[1][r]), fmaxf(sacc[2][r], sacc[3][r]));
#pragma unroll
    for (int off = 1; off < 16; off <<= 1)
#pragma unroll
      for (int r = 0; r < 4; ++r) tmax[r] = fmaxf(tmax[r], __shfl_xor(tmax[r], off, 64));

    float alpha[4], mne[4];
#pragma unroll
    for (int r = 0; r < 4; ++r) {
      const float mn = fmaxf(m_r[r], tmax[r]);
      mne[r] = (mn == -__builtin_inff()) ? 0.f : mn;  // fully-masked-row guard
      alpha[r] = __expf(m_r[r] - mne[r]);
      m_r[r] = mn;
    }

    float psum[4] = {0.f, 0.f, 0.f, 0.f};
    U16 pb[4][4];
#pragma unroll
    for (int nf = 0; nf < 4; ++nf)
#pragma unroll
      for (int r = 0; r < 4; ++r) {
        const float pv = __expf(sacc[nf][r] - mne[r]);
        psum[r] += pv;
        pb[nf][r] = f2bf(pv);
      }
#pragma unroll
    for (int off = 1; off < 16; off <<= 1)
#pragma unroll
      for (int r = 0; r < 4; ++r) psum[r] += __shfl_xor(psum[r], off, 64);
#pragma unroll
    for (int r = 0; r < 4; ++r) l_r[r] = l_r[r] * alpha[r] + psum[r];
#pragma unroll
    for (int i = 0; i < 8; ++i)
#pragma unroll
      for (int r = 0; r < 4; ++r) oacc[i][r] *= alpha[r];

    // P (C-layout) -> wave-local LDS -> A-frag relayout
#pragma unroll
    for (int nf = 0; nf < 4; ++nf)
#pragma unroll
      for (int r = 0; r < 4; ++r) pw[(fq * 4 + r) * 72 + nf * 16 + fr] = pb[nf][r];
    asm volatile("s_waitcnt lgkmcnt(0)" ::: "memory");
    const vbf8 pf0 = *(const vbf8*)(pw + fr * 72 + fq * 8);
    const vbf8 pf1 = *(const vbf8*)(pw + fr * 72 + 32 + fq * 8);

    // PV: V^T frags direct from global/L2
#pragma unroll
    for (int i = 0; i < 8; ++i) {
      const vbf8 v0 = *(const vbf8*)(vt_b + i * 16 * 2048 + s0);
      const vbf8 v1 = *(const vbf8*)(vt_b + i * 16 * 2048 + s0 + 32);
      oacc[i] = __builtin_amdgcn_mfma_f32_16x16x32_bf16(pf0, v0, oacc[i], 0, 0, 0);
      oacc[i] = __builtin_amdgcn_mfma_f32_16x16x32_bf16(pf1, v1, oacc[i], 0, 0, 0);
    }
  }

  // ---- 4-way s-split merge ----
  __syncthreads();
  float* O_p = (float*)smem;                    // [4][16][128]
  float* m_s = (float*)(smem + 32768);          // [4][16]
  float* l_s = (float*)(smem + 33024);          // [4][16]
#pragma unroll
  for (int i = 0; i < 8; ++i)
#pragma unroll
    for (int r = 0; r < 4; ++r)
      O_p[(w * 16 + fq * 4 + r) * 128 + i * 16 + fr] = oacc[i][r];
  if (fr == 0) {
#pragma unroll
    for (int r = 0; r < 4; ++r) {
      m_s[w * 16 + fq * 4 + r] = m_r[r];
      l_s[w * 16 + fq * 4 + r] = l_r[r];
    }
  }
  __syncthreads();

  const int row = tid >> 4, cg = tid & 15;
  float mv[4];
  float M = -__builtin_inff();
#pragma unroll
  for (int p = 0; p < 4; ++p) { mv[p] = m_s[p * 16 + row]; M = fmaxf(M, mv[p]); }
  float wgt[4], wsum = 0.f;
#pragma unroll
  for (int p = 0; p < 4; ++p) {
    wgt[p] = __expf(mv[p] - M);                 // mv=-inf (idle wave) -> 0
    wsum += wgt[p] * l_s[p * 16 + row];
  }
  const float inv = 1.f / wsum;                 // row always has s=0 valid -> wsum>0
  float o[8];
#pragma unroll
  for (int c = 0; c < 8; ++c) o[c] = 0.f;
#pragma unroll
  for (int p = 0; p < 4; ++p)
#pragma unroll
    for (int c = 0; c < 8; ++c) o[c] += wgt[p] * O_p[(p * 16 + row) * 128 + cg * 8 + c];
#pragma unroll
  for (int c = 0; c < 8; ++c)
    out[(size_t)(bb * 2048 + q0 + row) * 128 + cg * 8 + c] = o[c] * inv;
}

// ---------------- host ----------------------------------------------------------------
extern "C" void kernel_launch(void* const* d_in, const int* in_sizes, int n_in, void* d_out,
                              int out_size, void* d_ws, size_t ws_size, hipStream_t stream) {
  const float* x = (const float*)d_in[0];
  const float* wq = (const float*)d_in[1];
  const float* wk = (const float*)d_in[2];
  const float* wv = (const float*)d_in[3];
  char* ws = (char*)d_ws;
  // ws layout (bytes): total ~21.5 MB
  U16* wth = (U16*)(ws);              // 786432
  U16* wtl = (U16*)(ws + 786432);     // 786432
  U16* qh  = (U16*)(ws + 1572864);    // 4 MiB each below
  U16* ql  = (U16*)(ws + 5767168);
  U16* kh  = (U16*)(ws + 9961472);
  U16* kl  = (U16*)(ws + 14155776);
  U16* vt  = (U16*)(ws + 18350080);   // [8][128][2048] bf16
  float* out = (float*)d_out;

  wsplit_kernel<<<dim3(1536), dim3(256), 0, stream>>>(wq, wk, wv, wth, wtl);
  qkv_kernel<<<dim3(256, 3), dim3(256), 0, stream>>>(x, wth, wtl, qh, ql, kh, kl, vt);
  flash_kernel<<<dim3(1024), dim3(256), 0, stream>>>(qh, ql, kh, kl, vt, out);
}

// Round 5
// 135.596 us; speedup vs baseline: 1.1057x; 1.1057x over previous
//
#include <hip/hip_runtime.h>

// Head: x[8,2048,1024] fp32 -> q,k,v = x@w{q,k,v} -> causal softmax(q k^T * sqrt(128)) @ v
// Precision: bf16x3 split-GEMM for Q/K projections and QK^T (fp32-grade scores), bf16 V/PV.

#define NB 8
#define NT 2048
#define NE 1024
#define ND 128
#define NM (NB * NT)  // 16384

typedef unsigned short U16;
typedef unsigned int U32;
typedef __attribute__((ext_vector_type(8))) short vbf8;  // 8 bf16 (4 VGPR) MFMA frag
typedef __attribute__((ext_vector_type(4))) float vf4;   // MFMA 16x16 accum

__device__ __forceinline__ U16 f2bf(float f) {  // RNE fp32->bf16
  U32 u = __builtin_bit_cast(U32, f);
  u += 0x7fffu + ((u >> 16) & 1u);
  return (U16)(u >> 16);
}
__device__ __forceinline__ float bf2f(U16 h) {
  U32 u = ((U32)h) << 16;
  return __builtin_bit_cast(float, u);
}
__device__ __forceinline__ void gl_lds16(const void* g, void* l) {
  // async global->LDS, 16B per lane; LDS dest = wave-uniform base + lane*16
  __builtin_amdgcn_global_load_lds((__attribute__((address_space(1))) void*)g,
                                   (__attribute__((address_space(3))) void*)l, 16, 0, 0);
}

// ---------------- kernel 1: weight transpose + split (fold sqrt(128) into wq) ---------
__global__ void wsplit_kernel(const float* __restrict__ wq, const float* __restrict__ wk,
                              const float* __restrict__ wv, U16* __restrict__ wth,
                              U16* __restrict__ wtl) {
  int id = blockIdx.x * 256 + threadIdx.x;  // [0, 384*1024)
  if (id >= 384 * 1024) return;
  int n = id >> 10, e = id & 1023;
  float v;
  if (n < 128)      v = wq[e * 128 + n] * 11.313708498984761f;  // scores * d^0.5 folded in
  else if (n < 256) v = wk[e * 128 + (n - 128)];
  else              v = wv[e * 128 + (n - 256)];
  U16 h = f2bf(v);
  wth[id] = h;
  wtl[id] = f2bf(v - bf2f(h));
}

// ---------------- kernel 2: QKV projection, bf16x3 split GEMM ------------------------
// Tile 64(M)x128(N), BK=64. grid (256, 3): y 0->Q(hi/lo) 1->K(hi/lo) 2->V(bf16, vt).
// LDS layout [row][8 granules of 16B], granule XOR-swizzled by (row&7) on BOTH sides.
__global__ __launch_bounds__(256, 3) void qkv_kernel(
    const float* __restrict__ x, const U16* __restrict__ wth, const U16* __restrict__ wtl,
    U16* __restrict__ qh, U16* __restrict__ ql, U16* __restrict__ kh, U16* __restrict__ kl,
    U16* __restrict__ vt) {
  __shared__ __align__(16) char smem[49152];  // Ah/Al 8KB each, Bh/Bl 16KB each
  char* Ah = smem;
  char* Al = smem + 8192;
  char* Bh = smem + 16384;
  char* Bl = smem + 32768;

  const int tid = threadIdx.x;
  const int w = tid >> 6, lane = tid & 63;
  const int fr = lane & 15, fq = lane >> 4;
  const int m0 = blockIdx.x * 64;
  const int nt = blockIdx.y;
  const U16* bh_src = wth + nt * (128 * 1024);
  const U16* bl_src = wtl + nt * (128 * 1024);

  const vf4 vzero = {0.f, 0.f, 0.f, 0.f};
  vf4 acc[2][4];
#pragma unroll
  for (int i = 0; i < 2; ++i)
#pragma unroll
    for (int j = 0; j < 4; ++j) acc[i][j] = vzero;

  const int wm = (w >> 1) * 32, wn = (w & 1) * 64;  // wave tile 32x64
  const int arow = tid >> 2, ag = tid & 3;          // A stage: 2 granules (ag, ag+4)

  for (int k0 = 0; k0 < 1024; k0 += 64) {
    // --- async-stage B hi(/lo) [128 n][64 k], source-granule pre-swizzled ---
#pragma unroll
    for (int p = 0; p < 4; ++p) {
      const int g = p * 256 + tid;
      const int row = g >> 3, c = g & 7;
      const int sc = c ^ (row & 7);
      const int ldsb = (p * 256 + w * 64) * 16;  // wave-uniform granule base
      gl_lds16(bh_src + row * 1024 + k0 + sc * 8, Bh + ldsb);
      if (nt < 2) gl_lds16(bl_src + row * 1024 + k0 + sc * 8, Bl + ldsb);
    }
    // --- reg-stage + split A [64 m][64 k] from fp32 x, swizzled VALU stores ---
    {
      const float* s = x + (size_t)(m0 + arow) * 1024 + k0 + ag * 8;
      float v0[8], v1[8];
      ((float4*)v0)[0] = *(const float4*)(s);
      ((float4*)v0)[1] = *(const float4*)(s + 4);
      ((float4*)v1)[0] = *(const float4*)(s + 32);
      ((float4*)v1)[1] = *(const float4*)(s + 36);
      vbf8 h0, l0, h1, l1;
#pragma unroll
      for (int i = 0; i < 8; ++i) {
        U16 a = f2bf(v0[i]);
        h0[i] = (short)a; l0[i] = (short)f2bf(v0[i] - bf2f(a));
        U16 b = f2bf(v1[i]);
        h1[i] = (short)b; l1[i] = (short)f2bf(v1[i] - bf2f(b));
      }
      const int sw = arow & 7;
      *(vbf8*)(Ah + arow * 128 + ((ag ^ sw) << 4))       = h0;
      *(vbf8*)(Ah + arow * 128 + (((ag + 4) ^ sw) << 4)) = h1;
      if (nt < 2) {
        *(vbf8*)(Al + arow * 128 + ((ag ^ sw) << 4))       = l0;
        *(vbf8*)(Al + arow * 128 + (((ag + 4) ^ sw) << 4)) = l1;
      }
    }
    __syncthreads();

    if (nt < 2) {
#pragma unroll
      for (int kc = 0; kc < 2; ++kc) {
        vbf8 a_h[2], a_l[2], b_h[4], b_l[4];
#pragma unroll
        for (int i = 0; i < 2; ++i) {
          const int row = wm + i * 16 + fr;
          const int off = row * 128 + (((kc * 4 + fq) ^ (row & 7)) << 4);
          a_h[i] = *(const vbf8*)(Ah + off);
          a_l[i] = *(const vbf8*)(Al + off);
        }
#pragma unroll
        for (int j = 0; j < 4; ++j) {
          const int row = wn + j * 16 + fr;
          const int off = row * 128 + (((kc * 4 + fq) ^ (row & 7)) << 4);
          b_h[j] = *(const vbf8*)(Bh + off);
          b_l[j] = *(const vbf8*)(Bl + off);
        }
#pragma unroll
        for (int i = 0; i < 2; ++i)
#pragma unroll
          for (int j = 0; j < 4; ++j) {  // (Ah+Al)(Bh+Bl) dropping Al*Bl
            acc[i][j] = __builtin_amdgcn_mfma_f32_16x16x32_bf16(a_h[i], b_h[j], acc[i][j], 0, 0, 0);
            acc[i][j] = __builtin_amdgcn_mfma_f32_16x16x32_bf16(a_h[i], b_l[j], acc[i][j], 0, 0, 0);
            acc[i][j] = __builtin_amdgcn_mfma_f32_16x16x32_bf16(a_l[i], b_h[j], acc[i][j], 0, 0, 0);
          }
      }
    } else {  // V: hh only
#pragma unroll
      for (int kc = 0; kc < 2; ++kc) {
        vbf8 a_h[2], b_h[4];
#pragma unroll
        for (int i = 0; i < 2; ++i) {
          const int row = wm + i * 16 + fr;
          a_h[i] = *(const vbf8*)(Ah + row * 128 + (((kc * 4 + fq) ^ (row & 7)) << 4));
        }
#pragma unroll
        for (int j = 0; j < 4; ++j) {
          const int row = wn + j * 16 + fr;
          b_h[j] = *(const vbf8*)(Bh + row * 128 + (((kc * 4 + fq) ^ (row & 7)) << 4));
        }
#pragma unroll
        for (int i = 0; i < 2; ++i)
#pragma unroll
          for (int j = 0; j < 4; ++j)
            acc[i][j] = __builtin_amdgcn_mfma_f32_16x16x32_bf16(a_h[i], b_h[j], acc[i][j], 0, 0, 0);
      }
    }
    __syncthreads();
  }

  if (nt < 2) {  // Q or K: split hi/lo, natural [m][128] layout
    U16* dh = (nt == 0) ? qh : kh;
    U16* dl = (nt == 0) ? ql : kl;
#pragma unroll
    for (int i = 0; i < 2; ++i)
#pragma unroll
      for (int j = 0; j < 4; ++j)
#pragma unroll
        for (int r = 0; r < 4; ++r) {
          const int row = m0 + wm + i * 16 + fq * 4 + r;  // C/D: row=(lane>>4)*4+r
          const int col = wn + j * 16 + fr;               //      col=lane&15
          const float val = acc[i][j][r];
          const U16 h = f2bf(val);
          dh[row * 128 + col] = h;
          dl[row * 128 + col] = f2bf(val - bf2f(h));
        }
  } else {  // V: transpose via LDS -> vt[b][d][t], coalesced writeout
    U16* tl = (U16*)smem;  // [128 d][80] (pad kills conflicts; 20480 B < 48 KB)
#pragma unroll
    for (int i = 0; i < 2; ++i)
#pragma unroll
      for (int j = 0; j < 4; ++j)
#pragma unroll
        for (int r = 0; r < 4; ++r) {
          const int ml = wm + i * 16 + fq * 4 + r;
          const int col = wn + j * 16 + fr;
          tl[col * 80 + ml] = f2bf(acc[i][j][r]);
        }
    __syncthreads();
    const int bb = m0 >> 11, t0 = m0 & 2047;
#pragma unroll
    for (int p = 0; p < 4; ++p) {
      const int g = p * 256 + tid;
      const int d = g >> 3, c = g & 7;
      *(vbf8*)(vt + (size_t)(bb * 128 + d) * 2048 + t0 + c * 8) = *(const vbf8*)(tl + d * 80 + c * 8);
    }
  }
}

// ---------------- kernel 3: causal flash attention, pipelined LDS staging ------------
// grid 512 = 8 b x 64 q-tiles (desc/asc paired). Block = 2 waves (128 thr); each wave
// owns 16 q-rows x full 64-wide s-tile (no merge). K hi/lo reg-staged -> swizzled
// ds_write (issued 1 iter ahead); V^T double-buffered via global_load_lds (1 iter ahead).
// Counted vmcnt(8) before PV keeps next V-prefetch in flight; raw barriers only around
// the K LDS write.
__global__ __launch_bounds__(128) void flash_kernel(
    const U16* __restrict__ qh, const U16* __restrict__ ql, const U16* __restrict__ kh,
    const U16* __restrict__ kl, const U16* __restrict__ vt, float* __restrict__ out) {
  __shared__ __align__(16) char smem[70144];
  char* KhB = smem;                    // [64 s][128 d] bf16, granule^(row&7) swizzled
  char* KlB = smem + 16384;
  char* Vt0 = smem + 32768;            // [128 d][64 s] bf16, granule^(d&7) swizzled
  char* Vt1 = smem + 49152;
  U16* Pl = (U16*)(smem + 65536);      // [2 waves][16][72] (stride 72 = 9 granules, odd)

  const int tid = threadIdx.x;         // 0..127
  const int w = tid >> 6, lane = tid & 63;
  const int fr = lane & 15, fq = lane >> 4;
  const int bid = blockIdx.x;
  const int bb = bid & 7;              // batch -> XCD round-robin locality
  const int jj = bid >> 3;
  const int qt = (bid < 256) ? (63 - jj) : (jj - 32);  // heavy-first pairing
  const int q0 = qt * 32;
  const int nt = (qt + 2) >> 1;        // # of 64-wide s-tiles covering s <= q0+31

  const U16* khb = kh + (size_t)bb * 2048 * 128;
  const U16* klb = kl + (size_t)bb * 2048 * 128;
  const U16* vtb = vt + (size_t)bb * 128 * 2048;

  // K staging geometry (per thread, constant): row = i*8 + kr0, col granule kc16
  const int kr0 = tid >> 4;            // 0..7
  const int kc16 = tid & 15;           // 0..15
  const int cd = (kc16 ^ kr0) << 4;    // swizzled dest byte offset within row
  // V staging geometry: d = p*16 + vd0, source col pre-swizzled (dest is linear)
  const int vd0 = tid >> 3;            // 0..15
  const int cv = ((tid & 7) ^ (vd0 & 7)) * 8;  // element offset within d-row

  // hoisted Q fragments (A-frag: row=lane&15, k=(lane>>4)*8 + kc*32)
  vbf8 q_h[4], q_l[4];
  {
    const int rg = (bb * 2048 + q0 + w * 16 + fr) * 128 + fq * 8;
#pragma unroll
    for (int kc = 0; kc < 4; ++kc) {
      q_h[kc] = *(const vbf8*)(qh + rg + kc * 32);
      q_l[kc] = *(const vbf8*)(ql + rg + kc * 32);
    }
  }

  // ---- prologue: stage tile 0 (V async, K through regs) ----
  {
    char* vdst = Vt0 + w * 1024;
#pragma unroll
    for (int p = 0; p < 8; ++p)
      gl_lds16(vtb + (size_t)(p * 16 + vd0) * 2048 + cv, vdst + p * 2048);
    vbf8 k0[16];
#pragma unroll
    for (int i = 0; i < 8; ++i) {
      const int row = i * 8 + kr0;
      k0[i] = *(const vbf8*)(khb + (size_t)row * 128 + kc16 * 8);
      k0[i + 8] = *(const vbf8*)(klb + (size_t)row * 128 + kc16 * 8);
    }
#pragma unroll
    for (int i = 0; i < 8; ++i) {
      const int row = i * 8 + kr0;
      *(vbf8*)(KhB + row * 256 + cd) = k0[i];
      *(vbf8*)(KlB + row * 256 + cd) = k0[i + 8];
    }
    asm volatile("s_waitcnt lgkmcnt(0)" ::: "memory");
    __builtin_amdgcn_s_barrier();
  }

  const vf4 vzero = {0.f, 0.f, 0.f, 0.f};
  vf4 oacc[8];
#pragma unroll
  for (int i = 0; i < 8; ++i) oacc[i] = vzero;
  float m_r[4], l_r[4];
#pragma unroll
  for (int r = 0; r < 4; ++r) { m_r[r] = -__builtin_inff(); l_r[r] = 0.f; }

  for (int t = 0; t < nt; ++t) {
    const int s0 = t * 64;
    const bool pre = (t + 1 < nt);

    // ---- prefetch tile t+1: K -> regs (coalesced), V -> other LDS buffer (async) ----
    vbf8 kst[16];
    if (pre) {
      const int s0n = s0 + 64;
#pragma unroll
      for (int i = 0; i < 8; ++i) {
        const int row = i * 8 + kr0;
        kst[i] = *(const vbf8*)(khb + (size_t)(s0n + row) * 128 + kc16 * 8);
        kst[i + 8] = *(const vbf8*)(klb + (size_t)(s0n + row) * 128 + kc16 * 8);
      }
      char* vdst = ((t & 1) ? Vt0 : Vt1) + w * 1024;
#pragma unroll
      for (int p = 0; p < 8; ++p)
        gl_lds16(vtb + (size_t)(p * 16 + vd0) * 2048 + s0n + cv, vdst + p * 2048);
    }

    // ---- S = Q K^T (bf16x3) from swizzled K LDS ----
    vf4 sacc[4] = {vzero, vzero, vzero, vzero};
#pragma unroll
    for (int nf = 0; nf < 4; ++nf) {
      const int s_loc = nf * 16 + fr;
      const int swz = (s_loc & 7) << 4;
#pragma unroll
      for (int kc = 0; kc < 4; ++kc) {
        const int off = (s_loc * 256 + kc * 64 + fq * 16) ^ swz;
        const vbf8 kfh = *(const vbf8*)(KhB + off);
        const vbf8 kfl = *(const vbf8*)(KlB + off);
        sacc[nf] = __builtin_amdgcn_mfma_f32_16x16x32_bf16(q_h[kc], kfh, sacc[nf], 0, 0, 0);
        sacc[nf] = __builtin_amdgcn_mfma_f32_16x16x32_bf16(q_h[kc], kfl, sacc[nf], 0, 0, 0);
        sacc[nf] = __builtin_amdgcn_mfma_f32_16x16x32_bf16(q_l[kc], kfh, sacc[nf], 0, 0, 0);
      }
    }

    if (t == nt - 1) {  // causal mask (last tile only)
#pragma unroll
      for (int nf = 0; nf < 4; ++nf) {
        const int s_g = s0 + nf * 16 + fr;
#pragma unroll
        for (int r = 0; r < 4; ++r) {
          const int q_g = q0 + w * 16 + fq * 4 + r;
          if (s_g > q_g) sacc[nf][r] = -__builtin_inff();
        }
      }
    }

    // ---- online softmax; row-group = 16 consecutive lanes (same fq) ----
    float tmax[4];
#pragma unroll
    for (int r = 0; r < 4; ++r)
      tmax[r] = fmaxf(fmaxf(sacc[0][r], sacc[1][r]), fmaxf(sacc[2][r], sacc[3][r]));
#pragma unroll
    for (int off = 1; off < 16; off <<= 1)
#pragma unroll
      for (int r = 0; r < 4; ++r) tmax[r] = fmaxf(tmax[r], __shfl_xor(tmax[r], off, 64));

    float alpha[4], mne[4];
#pragma unroll
    for (int r = 0; r < 4; ++r) {
      const float mn = fmaxf(m_r[r], tmax[r]);
      mne[r] = (mn == -__builtin_inff()) ? 0.f : mn;
      alpha[r] = __expf(m_r[r] - mne[r]);
      m_r[r] = mn;
    }

    float psum[4] = {0.f, 0.f, 0.f, 0.f};
    U16 pb[4][4];
#pragma unroll
    for (int nf = 0; nf < 4; ++nf)
#pragma unroll
      for (int r = 0; r < 4; ++r) {
        const float pv = __expf(sacc[nf][r] - mne[r]);
        psum[r] += pv;
        pb[nf][r] = f2bf(pv);
      }
#pragma unroll
    for (int off = 1; off < 16; off <<= 1)
#pragma unroll
      for (int r = 0; r < 4; ++r) psum[r] += __shfl_xor(psum[r], off, 64);
#pragma unroll
    for (int r = 0; r < 4; ++r) l_r[r] = l_r[r] * alpha[r] + psum[r];
#pragma unroll
    for (int i = 0; i < 8; ++i)
#pragma unroll
      for (int r = 0; r < 4; ++r) oacc[i][r] *= alpha[r];

    // ---- P (C-layout) -> wave-local LDS -> A-frag relayout ----
    U16* pw = Pl + w * (16 * 72);
#pragma unroll
    for (int nf = 0; nf < 4; ++nf)
#pragma unroll
      for (int r = 0; r < 4; ++r) pw[(fq * 4 + r) * 72 + nf * 16 + fr] = pb[nf][r];
    asm volatile("s_waitcnt lgkmcnt(0)" ::: "memory");
    const vbf8 pf0 = *(const vbf8*)(pw + fr * 72 + fq * 8);
    const vbf8 pf1 = *(const vbf8*)(pw + fr * 72 + 32 + fq * 8);

    // ---- PV from V^T LDS buffer of tile t (counted wait keeps V(t+1) in flight) ----
    if (pre) asm volatile("s_waitcnt vmcnt(8)" ::: "memory");
    else     asm volatile("s_waitcnt vmcnt(0)" ::: "memory");
    const char* Vb = (t & 1) ? Vt1 : Vt0;
#pragma unroll
    for (int i = 0; i < 8; ++i) {
      const int d_loc = i * 16 + fr;
      const int vswz = (d_loc & 7) << 4;
      const vbf8 v0 = *(const vbf8*)(Vb + ((d_loc * 128 + fq * 16) ^ vswz));
      const vbf8 v1 = *(const vbf8*)(Vb + ((d_loc * 128 + 64 + fq * 16) ^ vswz));
      oacc[i] = __builtin_amdgcn_mfma_f32_16x16x32_bf16(pf0, v0, oacc[i], 0, 0, 0);
      oacc[i] = __builtin_amdgcn_mfma_f32_16x16x32_bf16(pf1, v1, oacc[i], 0, 0, 0);
    }

    // ---- commit K(t+1) regs to LDS (barrier-bracketed) ----
    if (pre) {
      __builtin_amdgcn_s_barrier();
#pragma unroll
      for (int i = 0; i < 8; ++i) {
        const int row = i * 8 + kr0;
        *(vbf8*)(KhB + row * 256 + cd) = kst[i];
        *(vbf8*)(KlB + row * 256 + cd) = kst[i + 8];
      }
      asm volatile("s_waitcnt lgkmcnt(0)" ::: "memory");
      __builtin_amdgcn_s_barrier();
    }
  }

  // ---- normalize + writeout (no merge needed) ----
  float inv[4];
#pragma unroll
  for (int r = 0; r < 4; ++r) inv[r] = 1.f / l_r[r];
#pragma unroll
  for (int i = 0; i < 8; ++i)
#pragma unroll
    for (int r = 0; r < 4; ++r) {
      const int row = q0 + w * 16 + fq * 4 + r;
      out[(size_t)(bb * 2048 + row) * 128 + i * 16 + fr] = oacc[i][r] * inv[r];
    }
}

// ---------------- host ----------------------------------------------------------------
extern "C" void kernel_launch(void* const* d_in, const int* in_sizes, int n_in, void* d_out,
                              int out_size, void* d_ws, size_t ws_size, hipStream_t stream) {
  const float* x = (const float*)d_in[0];
  const float* wq = (const float*)d_in[1];
  const float* wk = (const float*)d_in[2];
  const float* wv = (const float*)d_in[3];
  char* ws = (char*)d_ws;
  U16* wth = (U16*)(ws);              // 786432
  U16* wtl = (U16*)(ws + 786432);     // 786432
  U16* qh  = (U16*)(ws + 1572864);    // 4 MiB each below
  U16* ql  = (U16*)(ws + 5767168);
  U16* kh  = (U16*)(ws + 9961472);
  U16* kl  = (U16*)(ws + 14155776);
  U16* vt  = (U16*)(ws + 18350080);   // [8][128][2048] bf16
  float* out = (float*)d_out;

  wsplit_kernel<<<dim3(1536), dim3(256), 0, stream>>>(wq, wk, wv, wth, wtl);
  qkv_kernel<<<dim3(256, 3), dim3(256), 0, stream>>>(x, wth, wtl, qh, ql, kh, kl, vt);
  flash_kernel<<<dim3(512), dim3(128), 0, stream>>>(qh, ql, kh, kl, vt, out);
}

// Round 7
// 127.865 us; speedup vs baseline: 1.1726x; 1.0605x over previous
//
#include <hip/hip_runtime.h>

// Head: x[8,2048,1024] fp32 -> q,k,v = x@w{q,k,v} -> causal softmax(q k^T * sqrt(128)) @ v
// Precision: bf16x3 split-GEMM for Q/K projections and QK^T (fp32-grade scores), bf16 V/PV.

#define NB 8
#define NT 2048
#define NE 1024
#define ND 128
#define NM (NB * NT)  // 16384

typedef unsigned short U16;
typedef unsigned int U32;
typedef __attribute__((ext_vector_type(8))) short vbf8;  // 8 bf16 (4 VGPR) MFMA frag
typedef __attribute__((ext_vector_type(4))) float vf4;   // MFMA 16x16 accum

__device__ __forceinline__ U16 f2bf(float f) {  // RNE fp32->bf16
  U32 u = __builtin_bit_cast(U32, f);
  u += 0x7fffu + ((u >> 16) & 1u);
  return (U16)(u >> 16);
}
__device__ __forceinline__ float bf2f(U16 h) {
  U32 u = ((U32)h) << 16;
  return __builtin_bit_cast(float, u);
}
__device__ __forceinline__ void gl_lds16(const void* g, void* l) {
  // async global->LDS, 16B per lane; LDS dest = wave-uniform base + lane*16
  __builtin_amdgcn_global_load_lds((__attribute__((address_space(1))) void*)g,
                                   (__attribute__((address_space(3))) void*)l, 16, 0, 0);
}

// ---------------- kernel 1: weight transpose + split (fold sqrt(128) into wq) ---------
__global__ void wsplit_kernel(const float* __restrict__ wq, const float* __restrict__ wk,
                              const float* __restrict__ wv, U16* __restrict__ wth,
                              U16* __restrict__ wtl) {
  int id = blockIdx.x * 256 + threadIdx.x;  // [0, 384*1024)
  if (id >= 384 * 1024) return;
  int n = id >> 10, e = id & 1023;
  float v;
  if (n < 128)      v = wq[e * 128 + n] * 11.313708498984761f;  // scores * d^0.5 folded in
  else if (n < 256) v = wk[e * 128 + (n - 128)];
  else              v = wv[e * 128 + (n - 256)];
  U16 h = f2bf(v);
  wth[id] = h;
  wtl[id] = f2bf(v - bf2f(h));
}

// ---------------- kernel 2: QKV projection, bf16x3 split GEMM ------------------------
// Tile 64(M)x128(N), BK=64. grid (256, 3): y 0->Q(hi/lo) 1->K(hi/lo) 2->V(bf16, vt).
// LDS layout [row][8 granules of 16B], granule XOR-swizzled by (row&7) on BOTH sides.
__global__ __launch_bounds__(256, 3) void qkv_kernel(
    const float* __restrict__ x, const U16* __restrict__ wth, const U16* __restrict__ wtl,
    U16* __restrict__ qh, U16* __restrict__ ql, U16* __restrict__ kh, U16* __restrict__ kl,
    U16* __restrict__ vt) {
  __shared__ __align__(16) char smem[49152];  // Ah/Al 8KB each, Bh/Bl 16KB each
  char* Ah = smem;
  char* Al = smem + 8192;
  char* Bh = smem + 16384;
  char* Bl = smem + 32768;

  const int tid = threadIdx.x;
  const int w = tid >> 6, lane = tid & 63;
  const int fr = lane & 15, fq = lane >> 4;
  const int m0 = blockIdx.x * 64;
  const int nt = blockIdx.y;
  const U16* bh_src = wth + nt * (128 * 1024);
  const U16* bl_src = wtl + nt * (128 * 1024);

  const vf4 vzero = {0.f, 0.f, 0.f, 0.f};
  vf4 acc[2][4];
#pragma unroll
  for (int i = 0; i < 2; ++i)
#pragma unroll
    for (int j = 0; j < 4; ++j) acc[i][j] = vzero;

  const int wm = (w >> 1) * 32, wn = (w & 1) * 64;  // wave tile 32x64
  const int arow = tid >> 2, ag = tid & 3;          // A stage: 2 granules (ag, ag+4)

  for (int k0 = 0; k0 < 1024; k0 += 64) {
    // --- async-stage B hi(/lo) [128 n][64 k], source-granule pre-swizzled ---
#pragma unroll
    for (int p = 0; p < 4; ++p) {
      const int g = p * 256 + tid;
      const int row = g >> 3, c = g & 7;
      const int sc = c ^ (row & 7);
      const int ldsb = (p * 256 + w * 64) * 16;  // wave-uniform granule base
      gl_lds16(bh_src + row * 1024 + k0 + sc * 8, Bh + ldsb);
      if (nt < 2) gl_lds16(bl_src + row * 1024 + k0 + sc * 8, Bl + ldsb);
    }
    // --- reg-stage + split A [64 m][64 k] from fp32 x, swizzled VALU stores ---
    {
      const float* s = x + (size_t)(m0 + arow) * 1024 + k0 + ag * 8;
      float v0[8], v1[8];
      ((float4*)v0)[0] = *(const float4*)(s);
      ((float4*)v0)[1] = *(const float4*)(s + 4);
      ((float4*)v1)[0] = *(const float4*)(s + 32);
      ((float4*)v1)[1] = *(const float4*)(s + 36);
      vbf8 h0, l0, h1, l1;
#pragma unroll
      for (int i = 0; i < 8; ++i) {
        U16 a = f2bf(v0[i]);
        h0[i] = (short)a; l0[i] = (short)f2bf(v0[i] - bf2f(a));
        U16 b = f2bf(v1[i]);
        h1[i] = (short)b; l1[i] = (short)f2bf(v1[i] - bf2f(b));
      }
      const int sw = arow & 7;
      *(vbf8*)(Ah + arow * 128 + ((ag ^ sw) << 4))       = h0;
      *(vbf8*)(Ah + arow * 128 + (((ag + 4) ^ sw) << 4)) = h1;
      if (nt < 2) {
        *(vbf8*)(Al + arow * 128 + ((ag ^ sw) << 4))       = l0;
        *(vbf8*)(Al + arow * 128 + (((ag + 4) ^ sw) << 4)) = l1;
      }
    }
    __syncthreads();

    if (nt < 2) {
#pragma unroll
      for (int kc = 0; kc < 2; ++kc) {
        vbf8 a_h[2], a_l[2], b_h[4], b_l[4];
#pragma unroll
        for (int i = 0; i < 2; ++i) {
          const int row = wm + i * 16 + fr;
          const int off = row * 128 + (((kc * 4 + fq) ^ (row & 7)) << 4);
          a_h[i] = *(const vbf8*)(Ah + off);
          a_l[i] = *(const vbf8*)(Al + off);
        }
#pragma unroll
        for (int j = 0; j < 4; ++j) {
          const int row = wn + j * 16 + fr;
          const int off = row * 128 + (((kc * 4 + fq) ^ (row & 7)) << 4);
          b_h[j] = *(const vbf8*)(Bh + off);
          b_l[j] = *(const vbf8*)(Bl + off);
        }
#pragma unroll
        for (int i = 0; i < 2; ++i)
#pragma unroll
          for (int j = 0; j < 4; ++j) {  // (Ah+Al)(Bh+Bl) dropping Al*Bl
            acc[i][j] = __builtin_amdgcn_mfma_f32_16x16x32_bf16(a_h[i], b_h[j], acc[i][j], 0, 0, 0);
            acc[i][j] = __builtin_amdgcn_mfma_f32_16x16x32_bf16(a_h[i], b_l[j], acc[i][j], 0, 0, 0);
            acc[i][j] = __builtin_amdgcn_mfma_f32_16x16x32_bf16(a_l[i], b_h[j], acc[i][j], 0, 0, 0);
          }
      }
    } else {  // V: hh only
#pragma unroll
      for (int kc = 0; kc < 2; ++kc) {
        vbf8 a_h[2], b_h[4];
#pragma unroll
        for (int i = 0; i < 2; ++i) {
          const int row = wm + i * 16 + fr;
          a_h[i] = *(const vbf8*)(Ah + row * 128 + (((kc * 4 + fq) ^ (row & 7)) << 4));
        }
#pragma unroll
        for (int j = 0; j < 4; ++j) {
          const int row = wn + j * 16 + fr;
          b_h[j] = *(const vbf8*)(Bh + row * 128 + (((kc * 4 + fq) ^ (row & 7)) << 4));
        }
#pragma unroll
        for (int i = 0; i < 2; ++i)
#pragma unroll
          for (int j = 0; j < 4; ++j)
            acc[i][j] = __builtin_amdgcn_mfma_f32_16x16x32_bf16(a_h[i], b_h[j], acc[i][j], 0, 0, 0);
      }
    }
    __syncthreads();
  }

  if (nt < 2) {  // Q or K: split hi/lo, natural [m][128] layout
    U16* dh = (nt == 0) ? qh : kh;
    U16* dl = (nt == 0) ? ql : kl;
#pragma unroll
    for (int i = 0; i < 2; ++i)
#pragma unroll
      for (int j = 0; j < 4; ++j)
#pragma unroll
        for (int r = 0; r < 4; ++r) {
          const int row = m0 + wm + i * 16 + fq * 4 + r;  // C/D: row=(lane>>4)*4+r
          const int col = wn + j * 16 + fr;               //      col=lane&15
          const float val = acc[i][j][r];
          const U16 h = f2bf(val);
          dh[row * 128 + col] = h;
          dl[row * 128 + col] = f2bf(val - bf2f(h));
        }
  } else {  // V: transpose via LDS -> vt[b][d][t], coalesced writeout
    U16* tl = (U16*)smem;  // [128 d][80] (pad kills conflicts; 20480 B < 48 KB)
#pragma unroll
    for (int i = 0; i < 2; ++i)
#pragma unroll
      for (int j = 0; j < 4; ++j)
#pragma unroll
        for (int r = 0; r < 4; ++r) {
          const int ml = wm + i * 16 + fq * 4 + r;
          const int col = wn + j * 16 + fr;
          tl[col * 80 + ml] = f2bf(acc[i][j][r]);
        }
    __syncthreads();
    const int bb = m0 >> 11, t0 = m0 & 2047;
#pragma unroll
    for (int p = 0; p < 4; ++p) {
      const int g = p * 256 + tid;
      const int d = g >> 3, c = g & 7;
      *(vbf8*)(vt + (size_t)(bb * 128 + d) * 2048 + t0 + c * 8) = *(const vbf8*)(tl + d * 80 + c * 8);
    }
  }
}

// ---------------- kernel 3: causal flash attention, 8-wave blocks --------------------
// grid 512 = 8 b x 64 q-tiles (desc/asc paired), block 512 thr = 8 waves:
// wave (qg = w>>2) owns 16 q-rows, (sq = w&3) owns a 16-col s-quarter of SBLK=64.
// K hi/lo + V^T staged via source-swizzled global_load_lds (two 512-granule chunks per
// 16KB buffer); 16 waves/CU (2 blocks). PV pads P to k=32 with a pre-zeroed column
// block. 4-way s-quarter merge at the end per q-group.
__global__ __launch_bounds__(512, 4) void flash_kernel(
    const U16* __restrict__ qh, const U16* __restrict__ ql, const U16* __restrict__ kh,
    const U16* __restrict__ kl, const U16* __restrict__ vt, float* __restrict__ out) {
  __shared__ __align__(16) char smem[59392];
  char* KhB = smem;              // [64 s][128 d] bf16, granule^(s&7) swizzled
  char* KlB = smem + 16384;
  char* Vt  = smem + 32768;      // [128 d][64 s] bf16, granule^(d&7) swizzled
  // per-wave P: [16 q][40] u16 at 49152 + w*1280 (cols 0..15 live, 16..31 zero pad)
  // merge reuse: O_d [2][3][16][128] f32 (49152B) | m_s/l_s [2][4][16] f32 at 49152+

  const int tid = threadIdx.x;   // 0..511
  const int w = tid >> 6, lane = tid & 63;
  const int fr = lane & 15, fq = lane >> 4;
  const int qg = w >> 2, sq = w & 3;
  const int bid = blockIdx.x;
  const int bb = bid & 7;        // batch -> XCD round-robin locality
  const int jj = bid >> 3;
  const int qt = (bid < 256) ? (63 - jj) : (jj - 32);  // heavy-first pairing
  const int q0 = qt * 32;
  const int nt = (qt + 2) >> 1;  // # of 64-wide s-tiles covering s <= q0+31

  const U16* khb = kh + (size_t)bb * 2048 * 128;
  const U16* klb = kl + (size_t)bb * 2048 * 128;
  const U16* vtb = vt + (size_t)bb * 128 * 2048;
  U16* pw = (U16*)(smem + 49152 + w * 1280);  // [16][40]

  // zero the P pad (cols 16..31), wave-local, once
  *(U32*)(pw + fr * 40 + 16 + fq * 4) = 0u;
  *(U32*)(pw + fr * 40 + 18 + fq * 4) = 0u;

  // hoisted Q fragments (A-frag: row=lane&15, k=(lane>>4)*8 + kc*32)
  vbf8 q_h[4], q_l[4];
  {
    const int rg = (bb * 2048 + q0 + qg * 16 + fr) * 128 + fq * 8;
#pragma unroll
    for (int kc = 0; kc < 4; ++kc) {
      q_h[kc] = *(const vbf8*)(qh + rg + kc * 32);
      q_l[kc] = *(const vbf8*)(ql + rg + kc * 32);
    }
  }

  // K staging geometry: granule L=tid (rows 0..31) and L=512+tid (rows 32..63);
  // K row = 16 granules of 16B; source granule pre-swizzled by (row&7).
  const int kr0 = tid >> 4;                       // 0..31
  const int kg0 = tid & 15;
  const int ksc0 = ((kg0 ^ (kr0 & 7)) * 8);       // elements within row
  const int kr1 = 32 + kr0;                       // 32..63
  const int ksc1 = ((kg0 ^ (kr1 & 7)) * 8);
  // V staging geometry: granule L=tid (d 0..63) and L=512+tid (d 64..127);
  // V row = 8 granules; source granule pre-swizzled by (d&7).
  const int vd0 = tid >> 3;                       // 0..63
  const int vsc0 = (((tid & 7) ^ (vd0 & 7)) * 8);
  const int vd1 = 64 + vd0;                       // 64..127
  const int vsc1 = (((tid & 7) ^ (vd1 & 7)) * 8);

  const vf4 vzero = {0.f, 0.f, 0.f, 0.f};
  vf4 oacc[8];
#pragma unroll
  for (int i = 0; i < 8; ++i) oacc[i] = vzero;
  float m_r[4], l_r[4];
#pragma unroll
  for (int r = 0; r < 4; ++r) { m_r[r] = -__builtin_inff(); l_r[r] = 0.f; }

  const int s_loc = sq * 16 + fr;
  const int kswz = (s_loc & 7) << 4;

  for (int t = 0; t < nt; ++t) {
    const int s0 = t * 64;
    // ---- stage K hi/lo [64][128] + V^T [128][64] (source-side XOR swizzle) ----
    gl_lds16(khb + (size_t)(s0 + kr0) * 128 + ksc0, KhB + w * 1024);
    gl_lds16(khb + (size_t)(s0 + kr1) * 128 + ksc1, KhB + 8192 + w * 1024);
    gl_lds16(klb + (size_t)(s0 + kr0) * 128 + ksc0, KlB + w * 1024);
    gl_lds16(klb + (size_t)(s0 + kr1) * 128 + ksc1, KlB + 8192 + w * 1024);
    gl_lds16(vtb + (size_t)vd0 * 2048 + s0 + vsc0, Vt + w * 1024);
    gl_lds16(vtb + (size_t)vd1 * 2048 + s0 + vsc1, Vt + 8192 + w * 1024);
    __syncthreads();

    // ---- S = Q K^T (bf16x3): 12 MFMAs into one 16x16 frag ----
    vf4 sacc = vzero;
    __builtin_amdgcn_s_setprio(1);
#pragma unroll
    for (int kc = 0; kc < 4; ++kc) {
      const int off = (s_loc * 256 + kc * 64 + fq * 16) ^ kswz;
      const vbf8 kfh = *(const vbf8*)(KhB + off);
      const vbf8 kfl = *(const vbf8*)(KlB + off);
      sacc = __builtin_amdgcn_mfma_f32_16x16x32_bf16(q_h[kc], kfh, sacc, 0, 0, 0);
      sacc = __builtin_amdgcn_mfma_f32_16x16x32_bf16(q_h[kc], kfl, sacc, 0, 0, 0);
      sacc = __builtin_amdgcn_mfma_f32_16x16x32_bf16(q_l[kc], kfh, sacc, 0, 0, 0);
    }
    __builtin_amdgcn_s_setprio(0);

    if (t == nt - 1) {  // causal mask (last tile only)
      const int s_g = s0 + s_loc;
#pragma unroll
      for (int r = 0; r < 4; ++r) {
        const int q_g = q0 + qg * 16 + fq * 4 + r;
        if (s_g > q_g) sacc[r] = -__builtin_inff();
      }
    }

    // ---- online softmax over this wave's 16 s-cols (16-lane fr groups) ----
    float tmax[4];
#pragma unroll
    for (int r = 0; r < 4; ++r) tmax[r] = sacc[r];
#pragma unroll
    for (int off = 1; off < 16; off <<= 1)
#pragma unroll
      for (int r = 0; r < 4; ++r) tmax[r] = fmaxf(tmax[r], __shfl_xor(tmax[r], off, 64));

    float alpha[4], mne[4];
#pragma unroll
    for (int r = 0; r < 4; ++r) {
      const float mn = fmaxf(m_r[r], tmax[r]);
      mne[r] = (mn == -__builtin_inff()) ? 0.f : mn;  // fully-masked guard
      alpha[r] = __expf(m_r[r] - mne[r]);
      m_r[r] = mn;
    }

    float psum[4];
    U16 pb[4];
#pragma unroll
    for (int r = 0; r < 4; ++r) {
      const float pv = __expf(sacc[r] - mne[r]);
      psum[r] = pv;
      pb[r] = f2bf(pv);
    }
#pragma unroll
    for (int off = 1; off < 16; off <<= 1)
#pragma unroll
      for (int r = 0; r < 4; ++r) psum[r] += __shfl_xor(psum[r], off, 64);
#pragma unroll
    for (int r = 0; r < 4; ++r) l_r[r] = l_r[r] * alpha[r] + psum[r];
#pragma unroll
    for (int i = 0; i < 8; ++i)
#pragma unroll
      for (int r = 0; r < 4; ++r) oacc[i][r] *= alpha[r];

    // ---- P (C-layout) -> wave-local LDS -> A-frag relayout ----
#pragma unroll
    for (int r = 0; r < 4; ++r) pw[(fq * 4 + r) * 40 + fr] = pb[r];
    asm volatile("s_waitcnt lgkmcnt(0)" ::: "memory");
    const vbf8 pf = *(const vbf8*)(pw + fr * 40 + fq * 8);  // k 16..31 are zeros

    // ---- PV: 8 MFMAs; V junk rows (k>=16) multiplied by zero P ----
    const int s_v = (sq * 16 + fq * 8) & 63;
    __builtin_amdgcn_s_setprio(1);
#pragma unroll
    for (int i = 0; i < 8; ++i) {
      const int d_loc = i * 16 + fr;
      const int off = (d_loc * 128 + s_v * 2) ^ ((d_loc & 7) << 4);
      const vbf8 vfr = *(const vbf8*)(Vt + off);
      oacc[i] = __builtin_amdgcn_mfma_f32_16x16x32_bf16(pf, vfr, oacc[i], 0, 0, 0);
    }
    __builtin_amdgcn_s_setprio(0);
    __builtin_amdgcn_s_barrier();  // raw: reads consumed by MFMAs above; no drain needed
  }

  // ---- 4-way s-quarter merge per q-group ----
  __syncthreads();
  float* O_d = (float*)smem;                   // [2 qg][3][16][128]
  float* m_s = (float*)(smem + 49152);         // [2][4][16]
  float* l_s = (float*)(smem + 49664);         // [2][4][16]
  if (sq > 0) {
#pragma unroll
    for (int i = 0; i < 8; ++i)
#pragma unroll
      for (int r = 0; r < 4; ++r)
        O_d[((qg * 3 + sq - 1) * 16 + fq * 4 + r) * 128 + i * 16 + fr] = oacc[i][r];
  }
  if (fr == 0) {
#pragma unroll
    for (int r = 0; r < 4; ++r) {
      m_s[(qg * 4 + sq) * 16 + fq * 4 + r] = m_r[r];
      l_s[(qg * 4 + sq) * 16 + fq * 4 + r] = l_r[r];
    }
  }
  __syncthreads();
  if (sq == 0) {
#pragma unroll
    for (int r = 0; r < 4; ++r) {
      const int row = fq * 4 + r;
      float mv[4];
      float M = -__builtin_inff();
#pragma unroll
      for (int p = 0; p < 4; ++p) {
        mv[p] = m_s[(qg * 4 + p) * 16 + row];
        M = fmaxf(M, mv[p]);
      }
      float wgt[4], denom = 0.f;
#pragma unroll
      for (int p = 0; p < 4; ++p) {
        wgt[p] = __expf(mv[p] - M);            // -inf (fully masked quarter) -> 0
        denom += wgt[p] * l_s[(qg * 4 + p) * 16 + row];
      }
      const float inv = 1.f / denom;           // sq0 always has the diagonal -> denom>0
#pragma unroll
      for (int i = 0; i < 8; ++i) {
        float o = wgt[0] * oacc[i][r];
#pragma unroll
        for (int p = 1; p < 4; ++p)
          o += wgt[p] * O_d[((qg * 3 + p - 1) * 16 + row) * 128 + i * 16 + fr];
        out[(size_t)(bb * 2048 + q0 + qg * 16 + row) * 128 + i * 16 + fr] = o * inv;
      }
    }
  }
}

// ---------------- host ----------------------------------------------------------------
extern "C" void kernel_launch(void* const* d_in, const int* in_sizes, int n_in, void* d_out,
                              int out_size, void* d_ws, size_t ws_size, hipStream_t stream) {
  const float* x = (const float*)d_in[0];
  const float* wq = (const float*)d_in[1];
  const float* wk = (const float*)d_in[2];
  const float* wv = (const float*)d_in[3];
  char* ws = (char*)d_ws;
  U16* wth = (U16*)(ws);              // 786432
  U16* wtl = (U16*)(ws + 786432);     // 786432
  U16* qh  = (U16*)(ws + 1572864);    // 4 MiB each below
  U16* ql  = (U16*)(ws + 5767168);
  U16* kh  = (U16*)(ws + 9961472);
  U16* kl  = (U16*)(ws + 14155776);
  U16* vt  = (U16*)(ws + 18350080);   // [8][128][2048] bf16
  float* out = (float*)d_out;

  wsplit_kernel<<<dim3(1536), dim3(256), 0, stream>>>(wq, wk, wv, wth, wtl);
  qkv_kernel<<<dim3(256, 3), dim3(256), 0, stream>>>(x, wth, wtl, qh, ql, kh, kl, vt);
  flash_kernel<<<dim3(512), dim3(512), 0, stream>>>(qh, ql, kh, kl, vt, out);
}

// Round 8
// 105.324 us; speedup vs baseline: 1.4235x; 1.2140x over previous
//
#include <hip/hip_runtime.h>

// Head: x[8,2048,1024] fp32 -> q,k,v = x@w{q,k,v} -> causal softmax(q k^T * sqrt(128)) @ v
// Precision: bf16x3 split-GEMM for Q/K projections and QK^T (fp32-grade scores), bf16 V/PV.
// Q/K/V stored in MFMA-fragment-major layout (64-lane x 16B frags contiguous) so the
// flash kernel reads operands straight from L2 with perfect coalescing - no staging.

#define NB 8
#define NT 2048
#define NE 1024
#define ND 128

typedef unsigned short U16;
typedef unsigned int U32;
typedef __attribute__((ext_vector_type(8))) short vbf8;  // 8 bf16 (4 VGPR) MFMA frag
typedef __attribute__((ext_vector_type(4))) float vf4;   // MFMA 16x16 accum

__device__ __forceinline__ U16 f2bf(float f) {  // RNE fp32->bf16
  U32 u = __builtin_bit_cast(U32, f);
  u += 0x7fffu + ((u >> 16) & 1u);
  return (U16)(u >> 16);
}
__device__ __forceinline__ float bf2f(U16 h) {
  U32 u = ((U32)h) << 16;
  return __builtin_bit_cast(float, u);
}
__device__ __forceinline__ void gl_lds16(const void* g, void* l) {
  __builtin_amdgcn_global_load_lds((__attribute__((address_space(1))) void*)g,
                                   (__attribute__((address_space(3))) void*)l, 16, 0, 0);
}

// ---------------- kernel 1: weight transpose + split (fold sqrt(128) into wq) ---------
__global__ void wsplit_kernel(const float* __restrict__ wq, const float* __restrict__ wk,
                              const float* __restrict__ wv, U16* __restrict__ wth,
                              U16* __restrict__ wtl) {
  int id = blockIdx.x * 256 + threadIdx.x;  // [0, 384*1024)
  if (id >= 384 * 1024) return;
  int n = id >> 10, e = id & 1023;
  float v;
  if (n < 128)      v = wq[e * 128 + n] * 11.313708498984761f;  // scores * d^0.5 folded in
  else if (n < 256) v = wk[e * 128 + (n - 128)];
  else              v = wv[e * 128 + (n - 256)];
  U16 h = f2bf(v);
  wth[id] = h;
  wtl[id] = f2bf(v - bf2f(h));
}

// ---------------- kernel 2: QKV projection, bf16x3 split GEMM ------------------------
// Tile 64(M)x128(N), BK=64. grid (256, 3): y 0->Q(hi/lo frag) 1->K(hi/lo frag) 2->V(frag).
// GEMM-loop LDS layout [row][8 granules of 16B], granule XOR-swizzled by (row&7) both sides.
// Epilogues bounce C through padded LDS and emit fragment-major layouts:
//   q/k frag: [b][g=row/16][kc=d/32][lane][8]  elems = M[g*16+(l&15)][kc*32+(l>>4)*8+e]
//   v   frag: [b][df=d/16][sc=s/32][lane][8]   elems = V[sc*32+(l>>4)*8+e][df*16+(l&15)]
__global__ __launch_bounds__(256, 3) void qkv_kernel(
    const float* __restrict__ x, const U16* __restrict__ wth, const U16* __restrict__ wtl,
    U16* __restrict__ qfh, U16* __restrict__ qfl, U16* __restrict__ kfh,
    U16* __restrict__ kfl, U16* __restrict__ vf) {
  __shared__ __align__(16) char smem[49152];  // Ah/Al 8KB each, Bh/Bl 16KB each
  char* Ah = smem;
  char* Al = smem + 8192;
  char* Bh = smem + 16384;
  char* Bl = smem + 32768;

  const int tid = threadIdx.x;
  const int w = tid >> 6, lane = tid & 63;
  const int fr = lane & 15, fq = lane >> 4;
  const int m0 = blockIdx.x * 64;
  const int nt = blockIdx.y;
  const U16* bh_src = wth + nt * (128 * 1024);
  const U16* bl_src = wtl + nt * (128 * 1024);

  const vf4 vzero = {0.f, 0.f, 0.f, 0.f};
  vf4 acc[2][4];
#pragma unroll
  for (int i = 0; i < 2; ++i)
#pragma unroll
    for (int j = 0; j < 4; ++j) acc[i][j] = vzero;

  const int wm = (w >> 1) * 32, wn = (w & 1) * 64;  // wave tile 32x64
  const int arow = tid >> 2, ag = tid & 3;          // A stage: 2 granules (ag, ag+4)

  for (int k0 = 0; k0 < 1024; k0 += 64) {
    // --- async-stage B hi(/lo) [128 n][64 k], source-granule pre-swizzled ---
#pragma unroll
    for (int p = 0; p < 4; ++p) {
      const int g = p * 256 + tid;
      const int row = g >> 3, c = g & 7;
      const int sc = c ^ (row & 7);
      const int ldsb = (p * 256 + w * 64) * 16;  // wave-uniform granule base
      gl_lds16(bh_src + row * 1024 + k0 + sc * 8, Bh + ldsb);
      if (nt < 2) gl_lds16(bl_src + row * 1024 + k0 + sc * 8, Bl + ldsb);
    }
    // --- reg-stage + split A [64 m][64 k] from fp32 x, swizzled VALU stores ---
    {
      const float* s = x + (size_t)(m0 + arow) * 1024 + k0 + ag * 8;
      float v0[8], v1[8];
      ((float4*)v0)[0] = *(const float4*)(s);
      ((float4*)v0)[1] = *(const float4*)(s + 4);
      ((float4*)v1)[0] = *(const float4*)(s + 32);
      ((float4*)v1)[1] = *(const float4*)(s + 36);
      vbf8 h0, l0, h1, l1;
#pragma unroll
      for (int i = 0; i < 8; ++i) {
        U16 a = f2bf(v0[i]);
        h0[i] = (short)a; l0[i] = (short)f2bf(v0[i] - bf2f(a));
        U16 b = f2bf(v1[i]);
        h1[i] = (short)b; l1[i] = (short)f2bf(v1[i] - bf2f(b));
      }
      const int sw = arow & 7;
      *(vbf8*)(Ah + arow * 128 + ((ag ^ sw) << 4))       = h0;
      *(vbf8*)(Ah + arow * 128 + (((ag + 4) ^ sw) << 4)) = h1;
      if (nt < 2) {
        *(vbf8*)(Al + arow * 128 + ((ag ^ sw) << 4))       = l0;
        *(vbf8*)(Al + arow * 128 + (((ag + 4) ^ sw) << 4)) = l1;
      }
    }
    __syncthreads();

    if (nt < 2) {
#pragma unroll
      for (int kc = 0; kc < 2; ++kc) {
        vbf8 a_h[2], a_l[2], b_h[4], b_l[4];
#pragma unroll
        for (int i = 0; i < 2; ++i) {
          const int row = wm + i * 16 + fr;
          const int off = row * 128 + (((kc * 4 + fq) ^ (row & 7)) << 4);
          a_h[i] = *(const vbf8*)(Ah + off);
          a_l[i] = *(const vbf8*)(Al + off);
        }
#pragma unroll
        for (int j = 0; j < 4; ++j) {
          const int row = wn + j * 16 + fr;
          const int off = row * 128 + (((kc * 4 + fq) ^ (row & 7)) << 4);
          b_h[j] = *(const vbf8*)(Bh + off);
          b_l[j] = *(const vbf8*)(Bl + off);
        }
#pragma unroll
        for (int i = 0; i < 2; ++i)
#pragma unroll
          for (int j = 0; j < 4; ++j) {  // (Ah+Al)(Bh+Bl) dropping Al*Bl
            acc[i][j] = __builtin_amdgcn_mfma_f32_16x16x32_bf16(a_h[i], b_h[j], acc[i][j], 0, 0, 0);
            acc[i][j] = __builtin_amdgcn_mfma_f32_16x16x32_bf16(a_h[i], b_l[j], acc[i][j], 0, 0, 0);
            acc[i][j] = __builtin_amdgcn_mfma_f32_16x16x32_bf16(a_l[i], b_h[j], acc[i][j], 0, 0, 0);
          }
      }
    } else {  // V: hh only
#pragma unroll
      for (int kc = 0; kc < 2; ++kc) {
        vbf8 a_h[2], b_h[4];
#pragma unroll
        for (int i = 0; i < 2; ++i) {
          const int row = wm + i * 16 + fr;
          a_h[i] = *(const vbf8*)(Ah + row * 128 + (((kc * 4 + fq) ^ (row & 7)) << 4));
        }
#pragma unroll
        for (int j = 0; j < 4; ++j) {
          const int row = wn + j * 16 + fr;
          b_h[j] = *(const vbf8*)(Bh + row * 128 + (((kc * 4 + fq) ^ (row & 7)) << 4));
        }
#pragma unroll
        for (int i = 0; i < 2; ++i)
#pragma unroll
          for (int j = 0; j < 4; ++j)
            acc[i][j] = __builtin_amdgcn_mfma_f32_16x16x32_bf16(a_h[i], b_h[j], acc[i][j], 0, 0, 0);
      }
    }
    __syncthreads();
  }

  const int b = m0 >> 11;
  if (nt < 2) {  // Q or K: C -> padded LDS -> hi/lo fragment-major layout
    U16* tlh = (U16*)smem;            // [64][132]
    U16* tll = (U16*)(smem + 16896);  // [64][132]
#pragma unroll
    for (int i = 0; i < 2; ++i)
#pragma unroll
      for (int j = 0; j < 4; ++j)
#pragma unroll
        for (int r = 0; r < 4; ++r) {
          const int ml = wm + i * 16 + fq * 4 + r;   // C/D: row=(lane>>4)*4+r
          const int col = wn + j * 16 + fr;          //      col=lane&15
          const float val = acc[i][j][r];
          const U16 h = f2bf(val);
          tlh[ml * 132 + col] = h;
          tll[ml * 132 + col] = f2bf(val - bf2f(h));
        }
    __syncthreads();
    U16* dh = (nt == 0) ? qfh : kfh;
    U16* dl = (nt == 0) ? qfl : kfl;
    const int g0 = (m0 & 2047) >> 4;
#pragma unroll
    for (int p = 0; p < 4; ++p) {
      const int idx = p * 256 + tid;               // 0..1023
      const int gl = idx >> 8, kc = (idx >> 6) & 3, ln = idx & 63;
      const int row = gl * 16 + (ln & 15);
      const int colc = kc * 32 + (ln >> 4) * 8;
      const size_t o = (((size_t)b * 128 + g0 + gl) * 4 + kc) * 512 + ln * 8;
      *(vbf8*)(dh + o) = *(const vbf8*)(tlh + row * 132 + colc);
      *(vbf8*)(dl + o) = *(const vbf8*)(tll + row * 132 + colc);
    }
  } else {  // V: C -> padded LDS transpose -> fragment-major layout
    U16* tl = (U16*)smem;  // [128 d][68 s-local]
#pragma unroll
    for (int i = 0; i < 2; ++i)
#pragma unroll
      for (int j = 0; j < 4; ++j)
#pragma unroll
        for (int r = 0; r < 4; ++r) {
          const int ml = wm + i * 16 + fq * 4 + r;
          const int col = wn + j * 16 + fr;
          tl[col * 68 + ml] = f2bf(acc[i][j][r]);
        }
    __syncthreads();
    const int sc0 = (m0 & 2047) >> 5;  // 2 s-chunks per block
#pragma unroll
    for (int p = 0; p < 4; ++p) {
      const int idx = p * 256 + tid;               // 0..1023
      const int df = idx >> 7, sc = (idx >> 6) & 1, ln = idx & 63;
      const int d = df * 16 + (ln & 15);
      const int sl = sc * 32 + (ln >> 4) * 8;
      const size_t o = (((size_t)b * 8 + df) * 64 + (sc0 + sc)) * 512 + ln * 8;
      *(vbf8*)(vf + o) = *(const vbf8*)(tl + d * 68 + sl);
    }
  }
}

// ---------------- kernel 3: causal flash attention, barrier-free frag streaming ------
// grid 1024 = 8 b x 128 q-groups of 16 rows; block 256 thr = 4 waves, wave sq=0..3
// owns the sq-quarter (32 s-cols) of each 128-wide s-tile. K/V frags read directly
// from L2 (coalesced 1KB), zero staging, zero in-loop barriers; 4-way merge at end.
// g mapping (127-jj desc / jj-64 asc) makes the per-CU block sum constant.
__global__ __launch_bounds__(256, 3) void flash_kernel(
    const U16* __restrict__ qfh, const U16* __restrict__ qfl,
    const U16* __restrict__ kfh, const U16* __restrict__ kfl,
    const U16* __restrict__ vf, float* __restrict__ out) {
  __shared__ __align__(16) char smem[25088];
  // loop phase:  per-wave P buffer [16][40] U16 at smem + w*1280 (5120 B total)
  // merge phase: O_d [3][16][128] f32 (24576) | m_s [4][16] | l_s [4][16]

  const int tid = threadIdx.x;
  const int w = tid >> 6, lane = tid & 63;
  const int fr = lane & 15, fq = lane >> 4;
  const int sq = w;
  const int bid = blockIdx.x;
  const int bb = bid & 7;            // batch -> XCD round-robin locality
  const int jj = bid >> 3;           // 0..127
  const int g = (jj < 64) ? (127 - jj) : (jj - 64);
  const int q0g = g * 16;

  // hoisted Q A-frags (coalesced 1KB frag reads)
  vbf8 q_h[4], q_l[4];
  {
    const U16* qb = qfh + ((size_t)bb * 128 + g) * 2048 + lane * 8;
    const U16* qlb = qfl + ((size_t)bb * 128 + g) * 2048 + lane * 8;
#pragma unroll
    for (int kc = 0; kc < 4; ++kc) {
      q_h[kc] = *(const vbf8*)(qb + kc * 512);
      q_l[kc] = *(const vbf8*)(qlb + kc * 512);
    }
  }

  const U16* khp = kfh + (size_t)bb * 262144 + (size_t)(sq * 2) * 2048 + lane * 8;
  const U16* klp = kfl + (size_t)bb * 262144 + (size_t)(sq * 2) * 2048 + lane * 8;
  const U16* vfp = vf + (size_t)bb * 262144 + (size_t)sq * 512 + lane * 8;
  U16* pw = (U16*)(smem + w * 1280);  // [16][40]

  const vf4 vzero = {0.f, 0.f, 0.f, 0.f};
  vf4 oacc[8];
#pragma unroll
  for (int i = 0; i < 8; ++i) oacc[i] = vzero;
  float m_r[4], l_r[4];
#pragma unroll
  for (int r = 0; r < 4; ++r) { m_r[r] = -__builtin_inff(); l_r[r] = 0.f; }

  const int lim = q0g + 15 - sq * 32;          // wave skips tiles fully past diagonal
  const int ntw = (lim >= 0) ? ((lim >> 7) + 1) : 0;

  for (int T = 0; T < ntw; ++T) {
    // V frags for this tile's 32-s chunk (prefetched; consumed after softmax)
    vbf8 vreg[8];
#pragma unroll
    for (int df = 0; df < 8; ++df) vreg[df] = *(const vbf8*)(vfp + df * 32768);

    // S = Q K^T (bf16x3): 2 s-frags x 4 kc x 3 = 24 MFMAs, K frags straight from L2
    vf4 sacc[2] = {vzero, vzero};
    __builtin_amdgcn_s_setprio(1);
#pragma unroll
    for (int sf2 = 0; sf2 < 2; ++sf2) {
#pragma unroll
      for (int kc = 0; kc < 4; ++kc) {
        const vbf8 kh_r = *(const vbf8*)(khp + sf2 * 2048 + kc * 512);
        const vbf8 kl_r = *(const vbf8*)(klp + sf2 * 2048 + kc * 512);
        sacc[sf2] = __builtin_amdgcn_mfma_f32_16x16x32_bf16(q_h[kc], kh_r, sacc[sf2], 0, 0, 0);
        sacc[sf2] = __builtin_amdgcn_mfma_f32_16x16x32_bf16(q_h[kc], kl_r, sacc[sf2], 0, 0, 0);
        sacc[sf2] = __builtin_amdgcn_mfma_f32_16x16x32_bf16(q_l[kc], kh_r, sacc[sf2], 0, 0, 0);
      }
    }
    __builtin_amdgcn_s_setprio(0);

    if (T == ntw - 1) {  // causal mask (each wave's last tile is its only partial one)
#pragma unroll
      for (int sf2 = 0; sf2 < 2; ++sf2) {
        const int s_g = T * 128 + sq * 32 + sf2 * 16 + fr;
#pragma unroll
        for (int r = 0; r < 4; ++r)
          if (s_g > q0g + fq * 4 + r) sacc[sf2][r] = -__builtin_inff();
      }
    }

    // online softmax over the wave's 32 s-cols (16-lane fr groups)
    float tmax[4];
#pragma unroll
    for (int r = 0; r < 4; ++r) tmax[r] = fmaxf(sacc[0][r], sacc[1][r]);
#pragma unroll
    for (int off = 1; off < 16; off <<= 1)
#pragma unroll
      for (int r = 0; r < 4; ++r) tmax[r] = fmaxf(tmax[r], __shfl_xor(tmax[r], off, 64));

    float alpha[4], mne[4];
#pragma unroll
    for (int r = 0; r < 4; ++r) {
      const float mn = fmaxf(m_r[r], tmax[r]);
      mne[r] = (mn == -__builtin_inff()) ? 0.f : mn;  // fully-masked guard
      alpha[r] = __expf(m_r[r] - mne[r]);
      m_r[r] = mn;
    }

    float psum[4];
    U16 pb[2][4];
#pragma unroll
    for (int sf2 = 0; sf2 < 2; ++sf2)
#pragma unroll
      for (int r = 0; r < 4; ++r) {
        const float pv = __expf(sacc[sf2][r] - mne[r]);
        psum[r] = (sf2 == 0) ? pv : (psum[r] + pv);
        pb[sf2][r] = f2bf(pv);
      }
#pragma unroll
    for (int off = 1; off < 16; off <<= 1)
#pragma unroll
      for (int r = 0; r < 4; ++r) psum[r] += __shfl_xor(psum[r], off, 64);
#pragma unroll
    for (int r = 0; r < 4; ++r) l_r[r] = l_r[r] * alpha[r] + psum[r];
#pragma unroll
    for (int i = 0; i < 8; ++i)
#pragma unroll
      for (int r = 0; r < 4; ++r) oacc[i][r] *= alpha[r];

    // P (C-layout) -> wave-private LDS -> A-frag (16x32, all cols live)
#pragma unroll
    for (int sf2 = 0; sf2 < 2; ++sf2)
#pragma unroll
      for (int r = 0; r < 4; ++r) pw[(fq * 4 + r) * 40 + sf2 * 16 + fr] = pb[sf2][r];
    asm volatile("s_waitcnt lgkmcnt(0)" ::: "memory");
    const vbf8 pf = *(const vbf8*)(pw + fr * 40 + fq * 8);

    // PV: 8 MFMAs from prefetched V regs
    __builtin_amdgcn_s_setprio(1);
#pragma unroll
    for (int df = 0; df < 8; ++df)
      oacc[df] = __builtin_amdgcn_mfma_f32_16x16x32_bf16(pf, vreg[df], oacc[df], 0, 0, 0);
    __builtin_amdgcn_s_setprio(0);

    khp += 16384; klp += 16384; vfp += 2048;  // next 128-wide tile
  }

  // ---- 4-way s-quarter merge (only barriers in the kernel) ----
  __syncthreads();
  float* O_d = (float*)smem;                 // [3][16][128]
  float* m_s = (float*)(smem + 24576);       // [4][16]
  float* l_s = (float*)(smem + 24832);       // [4][16]
  if (sq > 0) {
#pragma unroll
    for (int i = 0; i < 8; ++i)
#pragma unroll
      for (int r = 0; r < 4; ++r)
        O_d[((sq - 1) * 16 + fq * 4 + r) * 128 + i * 16 + fr] = oacc[i][r];
  }
  if (fr == 0) {
#pragma unroll
    for (int r = 0; r < 4; ++r) {
      m_s[sq * 16 + fq * 4 + r] = m_r[r];
      l_s[sq * 16 + fq * 4 + r] = l_r[r];
    }
  }
  __syncthreads();
  if (sq == 0) {
#pragma unroll
    for (int r = 0; r < 4; ++r) {
      const int row = fq * 4 + r;
      float mv[4];
      float M = -__builtin_inff();
#pragma unroll
      for (int p = 0; p < 4; ++p) {
        mv[p] = m_s[p * 16 + row];
        M = fmaxf(M, mv[p]);
      }
      float wgt[4], denom = 0.f;
#pragma unroll
      for (int p = 0; p < 4; ++p) {
        wgt[p] = __expf(mv[p] - M);            // -inf (idle/masked quarter) -> 0
        denom += wgt[p] * l_s[p * 16 + row];
      }
      const float inv = 1.f / denom;           // sq0 always has the diagonal -> denom>0
#pragma unroll
      for (int i = 0; i < 8; ++i) {
        float o = wgt[0] * oacc[i][r];
#pragma unroll
        for (int p = 1; p < 4; ++p)
          o += wgt[p] * O_d[((p - 1) * 16 + row) * 128 + i * 16 + fr];
        out[(size_t)(bb * 2048 + q0g + row) * 128 + i * 16 + fr] = o * inv;
      }
    }
  }
}

// ---------------- host ----------------------------------------------------------------
extern "C" void kernel_launch(void* const* d_in, const int* in_sizes, int n_in, void* d_out,
                              int out_size, void* d_ws, size_t ws_size, hipStream_t stream) {
  const float* x = (const float*)d_in[0];
  const float* wq = (const float*)d_in[1];
  const float* wk = (const float*)d_in[2];
  const float* wv = (const float*)d_in[3];
  char* ws = (char*)d_ws;
  U16* wth = (U16*)(ws);              // 768 KB
  U16* wtl = (U16*)(ws + 786432);     // 768 KB
  U16* qfh = (U16*)(ws + 1572864);    // 4 MiB each below (fragment-major)
  U16* qfl = (U16*)(ws + 5767168);
  U16* kfh = (U16*)(ws + 9961472);
  U16* kfl = (U16*)(ws + 14155776);
  U16* vfr = (U16*)(ws + 18350080);
  float* out = (float*)d_out;

  wsplit_kernel<<<dim3(1536), dim3(256), 0, stream>>>(wq, wk, wv, wth, wtl);
  qkv_kernel<<<dim3(256, 3), dim3(256), 0, stream>>>(x, wth, wtl, qfh, qfl, kfh, kfl, vfr);
  flash_kernel<<<dim3(1024), dim3(256), 0, stream>>>(qfh, qfl, kfh, kfl, vfr, out);
}

// Round 10
// 94.066 us; speedup vs baseline: 1.5939x; 1.1197x over previous
//
#include <hip/hip_runtime.h>

// Head: x[8,2048,1024] fp32 -> q,k,v = x@w{q,k,v} -> causal softmax(q k^T * sqrt(128)) @ v
// Precision: bf16x3 split-GEMM for Q/K projections and QK^T (fp32-grade scores), bf16 V/PV.
// Q/K/V stored in MFMA-fragment-major layout (64-lane x 16B frags contiguous) so the
// flash kernel reads operands straight from L2 with perfect coalescing - no staging.
// Softmax runs in log2 domain (log2e folded into wq).

#define NB 8
#define NT 2048
#define NE 1024
#define ND 128

typedef unsigned short U16;
typedef unsigned int U32;
typedef __attribute__((ext_vector_type(8))) short vbf8;  // 8 bf16 (4 VGPR) MFMA frag
typedef __attribute__((ext_vector_type(4))) float vf4;   // MFMA 16x16 accum

#define EXP2F(x) __builtin_amdgcn_exp2f(x)  // v_exp_f32: D = 2^S0

__device__ __forceinline__ U16 f2bf(float f) {  // RNE fp32->bf16
  U32 u = __builtin_bit_cast(U32, f);
  u += 0x7fffu + ((u >> 16) & 1u);
  return (U16)(u >> 16);
}
__device__ __forceinline__ float bf2f(U16 h) {
  U32 u = ((U32)h) << 16;
  return __builtin_bit_cast(float, u);
}
__device__ __forceinline__ void gl_lds16(const void* g, void* l) {
  __builtin_amdgcn_global_load_lds((__attribute__((address_space(1))) void*)g,
                                   (__attribute__((address_space(3))) void*)l, 16, 0, 0);
}

// ---------------- kernel 1: weight transpose + split (fold sqrt(128)*log2e into wq) ---
__global__ void wsplit_kernel(const float* __restrict__ wq, const float* __restrict__ wk,
                              const float* __restrict__ wv, U16* __restrict__ wth,
                              U16* __restrict__ wtl) {
  int id = blockIdx.x * 256 + threadIdx.x;  // [0, 384*1024)
  if (id >= 384 * 1024) return;
  int n = id >> 10, e = id & 1023;
  float v;
  if (n < 128)      v = wq[e * 128 + n] * 16.322231701033217f;  // sqrt(128)*log2(e)
  else if (n < 256) v = wk[e * 128 + (n - 128)];
  else              v = wv[e * 128 + (n - 256)];
  U16 h = f2bf(v);
  wth[id] = h;
  wtl[id] = f2bf(v - bf2f(h));
}

// ---------------- kernel 2: QKV projection, bf16x3 split GEMM ------------------------
// Tile 64(M)x128(N), BK=64. grid (256, 3): y 0->Q(hi/lo frag) 1->K(hi/lo frag) 2->V(frag).
// GEMM-loop LDS layout [row][8 granules of 16B], granule XOR-swizzled by (row&7) both sides.
// Epilogues bounce C through padded LDS and emit fragment-major layouts:
//   q/k frag: [b][g=row/16][kc=d/32][lane][8]  elems = M[g*16+(l&15)][kc*32+(l>>4)*8+e]
//   v   frag: [b][df=d/16][sc=s/32][lane][8]   elems = V[sc*32+(l>>4)*8+e][df*16+(l&15)]
__global__ __launch_bounds__(256, 3) void qkv_kernel(
    const float* __restrict__ x, const U16* __restrict__ wth, const U16* __restrict__ wtl,
    U16* __restrict__ qfh, U16* __restrict__ qfl, U16* __restrict__ kfh,
    U16* __restrict__ kfl, U16* __restrict__ vf) {
  __shared__ __align__(16) char smem[49152];  // Ah/Al 8KB each, Bh/Bl 16KB each
  char* Ah = smem;
  char* Al = smem + 8192;
  char* Bh = smem + 16384;
  char* Bl = smem + 32768;

  const int tid = threadIdx.x;
  const int w = tid >> 6, lane = tid & 63;
  const int fr = lane & 15, fq = lane >> 4;
  const int m0 = blockIdx.x * 64;
  const int nt = blockIdx.y;
  const U16* bh_src = wth + nt * (128 * 1024);
  const U16* bl_src = wtl + nt * (128 * 1024);

  const vf4 vzero = {0.f, 0.f, 0.f, 0.f};
  vf4 acc[2][4];
#pragma unroll
  for (int i = 0; i < 2; ++i)
#pragma unroll
    for (int j = 0; j < 4; ++j) acc[i][j] = vzero;

  const int wm = (w >> 1) * 32, wn = (w & 1) * 64;  // wave tile 32x64
  const int arow = tid >> 2, ag = tid & 3;          // A stage: 2 granules (ag, ag+4)

  for (int k0 = 0; k0 < 1024; k0 += 64) {
    // --- async-stage B hi(/lo) [128 n][64 k], source-granule pre-swizzled ---
#pragma unroll
    for (int p = 0; p < 4; ++p) {
      const int g = p * 256 + tid;
      const int row = g >> 3, c = g & 7;
      const int sc = c ^ (row & 7);
      const int ldsb = (p * 256 + w * 64) * 16;  // wave-uniform granule base
      gl_lds16(bh_src + row * 1024 + k0 + sc * 8, Bh + ldsb);
      if (nt < 2) gl_lds16(bl_src + row * 1024 + k0 + sc * 8, Bl + ldsb);
    }
    // --- reg-stage + split A [64 m][64 k] from fp32 x, swizzled VALU stores ---
    {
      const float* s = x + (size_t)(m0 + arow) * 1024 + k0 + ag * 8;
      float v0[8], v1[8];
      ((float4*)v0)[0] = *(const float4*)(s);
      ((float4*)v0)[1] = *(const float4*)(s + 4);
      ((float4*)v1)[0] = *(const float4*)(s + 32);
      ((float4*)v1)[1] = *(const float4*)(s + 36);
      vbf8 h0, l0, h1, l1;
#pragma unroll
      for (int i = 0; i < 8; ++i) {
        U16 a = f2bf(v0[i]);
        h0[i] = (short)a; l0[i] = (short)f2bf(v0[i] - bf2f(a));
        U16 b = f2bf(v1[i]);
        h1[i] = (short)b; l1[i] = (short)f2bf(v1[i] - bf2f(b));
      }
      const int sw = arow & 7;
      *(vbf8*)(Ah + arow * 128 + ((ag ^ sw) << 4))       = h0;
      *(vbf8*)(Ah + arow * 128 + (((ag + 4) ^ sw) << 4)) = h1;
      if (nt < 2) {
        *(vbf8*)(Al + arow * 128 + ((ag ^ sw) << 4))       = l0;
        *(vbf8*)(Al + arow * 128 + (((ag + 4) ^ sw) << 4)) = l1;
      }
    }
    __syncthreads();

    if (nt < 2) {
#pragma unroll
      for (int kc = 0; kc < 2; ++kc) {
        vbf8 a_h[2], a_l[2], b_h[4], b_l[4];
#pragma unroll
        for (int i = 0; i < 2; ++i) {
          const int row = wm + i * 16 + fr;
          const int off = row * 128 + (((kc * 4 + fq) ^ (row & 7)) << 4);
          a_h[i] = *(const vbf8*)(Ah + off);
          a_l[i] = *(const vbf8*)(Al + off);
        }
#pragma unroll
        for (int j = 0; j < 4; ++j) {
          const int row = wn + j * 16 + fr;
          const int off = row * 128 + (((kc * 4 + fq) ^ (row & 7)) << 4);
          b_h[j] = *(const vbf8*)(Bh + off);
          b_l[j] = *(const vbf8*)(Bl + off);
        }
#pragma unroll
        for (int i = 0; i < 2; ++i)
#pragma unroll
          for (int j = 0; j < 4; ++j) {  // (Ah+Al)(Bh+Bl) dropping Al*Bl
            acc[i][j] = __builtin_amdgcn_mfma_f32_16x16x32_bf16(a_h[i], b_h[j], acc[i][j], 0, 0, 0);
            acc[i][j] = __builtin_amdgcn_mfma_f32_16x16x32_bf16(a_h[i], b_l[j], acc[i][j], 0, 0, 0);
            acc[i][j] = __builtin_amdgcn_mfma_f32_16x16x32_bf16(a_l[i], b_h[j], acc[i][j], 0, 0, 0);
          }
      }
    } else {  // V: hh only
#pragma unroll
      for (int kc = 0; kc < 2; ++kc) {
        vbf8 a_h[2], b_h[4];
#pragma unroll
        for (int i = 0; i < 2; ++i) {
          const int row = wm + i * 16 + fr;
          a_h[i] = *(const vbf8*)(Ah + row * 128 + (((kc * 4 + fq) ^ (row & 7)) << 4));
        }
#pragma unroll
        for (int j = 0; j < 4; ++j) {
          const int row = wn + j * 16 + fr;
          b_h[j] = *(const vbf8*)(Bh + row * 128 + (((kc * 4 + fq) ^ (row & 7)) << 4));
        }
#pragma unroll
        for (int i = 0; i < 2; ++i)
#pragma unroll
          for (int j = 0; j < 4; ++j)
            acc[i][j] = __builtin_amdgcn_mfma_f32_16x16x32_bf16(a_h[i], b_h[j], acc[i][j], 0, 0, 0);
      }
    }
    __syncthreads();
  }

  const int b = m0 >> 11;
  if (nt < 2) {  // Q or K: C -> padded LDS -> hi/lo fragment-major layout
    U16* tlh = (U16*)smem;            // [64][132]
    U16* tll = (U16*)(smem + 16896);  // [64][132]
#pragma unroll
    for (int i = 0; i < 2; ++i)
#pragma unroll
      for (int j = 0; j < 4; ++j)
#pragma unroll
        for (int r = 0; r < 4; ++r) {
          const int ml = wm + i * 16 + fq * 4 + r;   // C/D: row=(lane>>4)*4+r
          const int col = wn + j * 16 + fr;          //      col=lane&15
          const float val = acc[i][j][r];
          const U16 h = f2bf(val);
          tlh[ml * 132 + col] = h;
          tll[ml * 132 + col] = f2bf(val - bf2f(h));
        }
    __syncthreads();
    U16* dh = (nt == 0) ? qfh : kfh;
    U16* dl = (nt == 0) ? qfl : kfl;
    const int g0 = (m0 & 2047) >> 4;
#pragma unroll
    for (int p = 0; p < 4; ++p) {
      const int idx = p * 256 + tid;               // 0..1023
      const int gl = idx >> 8, kc = (idx >> 6) & 3, ln = idx & 63;
      const int row = gl * 16 + (ln & 15);
      const int colc = kc * 32 + (ln >> 4) * 8;
      const size_t o = (((size_t)b * 128 + g0 + gl) * 4 + kc) * 512 + ln * 8;
      *(vbf8*)(dh + o) = *(const vbf8*)(tlh + row * 132 + colc);
      *(vbf8*)(dl + o) = *(const vbf8*)(tll + row * 132 + colc);
    }
  } else {  // V: C -> padded LDS transpose -> fragment-major layout
    U16* tl = (U16*)smem;  // [128 d][68 s-local]
#pragma unroll
    for (int i = 0; i < 2; ++i)
#pragma unroll
      for (int j = 0; j < 4; ++j)
#pragma unroll
        for (int r = 0; r < 4; ++r) {
          const int ml = wm + i * 16 + fq * 4 + r;
          const int col = wn + j * 16 + fr;
          tl[col * 68 + ml] = f2bf(acc[i][j][r]);
        }
    __syncthreads();
    const int sc0 = (m0 & 2047) >> 5;  // 2 s-chunks per block
#pragma unroll
    for (int p = 0; p < 4; ++p) {
      const int idx = p * 256 + tid;               // 0..1023
      const int df = idx >> 7, sc = (idx >> 6) & 1, ln = idx & 63;
      const int d = df * 16 + (ln & 15);
      const int sl = sc * 32 + (ln >> 4) * 8;
      const size_t o = (((size_t)b * 8 + df) * 64 + (sc0 + sc)) * 512 + ln * 8;
      *(vbf8*)(vf + o) = *(const vbf8*)(tl + d * 68 + sl);
    }
  }
}

// ---------------- kernel 3: causal flash attention, SBLK=256 frag streaming ----------
// grid 1024 = 8 b x 128 q-groups of 16 rows; block 256 thr = 4 waves, wave sq=0..3
// owns the sq-quarter (64 s-cols = 4 frags) of each 256-wide s-tile. K/V frags read
// directly from L2 (coalesced 1KB), zero staging, zero in-loop barriers. Softmax in
// log2 domain; O-rescale skipped (exact) when no row max grows. 4-way merge at end.
__global__ __launch_bounds__(256, 3) void flash_kernel(
    const U16* __restrict__ qfh, const U16* __restrict__ qfl,
    const U16* __restrict__ kfh, const U16* __restrict__ kfl,
    const U16* __restrict__ vf, float* __restrict__ out) {
  __shared__ __align__(16) char smem[25088];
  // loop phase:  per-wave P buffer [16][72] U16 at smem + w*2304 (9216 B total)
  // merge phase: O_d [3][16][128] f32 (24576) | m_s [4][16] | l_s [4][16]

  const int tid = threadIdx.x;
  const int w = tid >> 6, lane = tid & 63;
  const int fr = lane & 15, fq = lane >> 4;
  const int sq = w;
  const int bid = blockIdx.x;
  const int bb = bid & 7;            // batch -> XCD round-robin locality
  const int jj = bid >> 3;           // 0..127
  const int g = (jj < 64) ? (127 - jj) : (jj - 64);
  const int q0g = g * 16;

  // hoisted Q A-frags (coalesced 1KB frag reads)
  vbf8 q_h[4], q_l[4];
  {
    const U16* qb = qfh + ((size_t)bb * 128 + g) * 2048 + lane * 8;
    const U16* qlb = qfl + ((size_t)bb * 128 + g) * 2048 + lane * 8;
#pragma unroll
    for (int kc = 0; kc < 4; ++kc) {
      q_h[kc] = *(const vbf8*)(qb + kc * 512);
      q_l[kc] = *(const vbf8*)(qlb + kc * 512);
    }
  }

  // K frags: [b][sfi=s/16][kc][512]; wave's frags sfi = T*16 + sq*4 + sf
  const U16* khp = kfh + (size_t)bb * 262144 + (size_t)(sq * 4) * 2048 + lane * 8;
  const U16* klp = kfl + (size_t)bb * 262144 + (size_t)(sq * 4) * 2048 + lane * 8;
  // V frags: [b][df][sc=s/32][512]; wave's chunks sc = T*8 + sq*2 + c
  const U16* vfp = vf + (size_t)bb * 262144 + (size_t)(sq * 2) * 512 + lane * 8;
  U16* pw = (U16*)(smem + w * 2304);  // [16][72]

  const vf4 vzero = {0.f, 0.f, 0.f, 0.f};
  vf4 oacc[8];
#pragma unroll
  for (int i = 0; i < 8; ++i) oacc[i] = vzero;
  float m_r[4], l_r[4];
#pragma unroll
  for (int r = 0; r < 4; ++r) { m_r[r] = -__builtin_inff(); l_r[r] = 0.f; }

  const int lim = q0g + 15 - sq * 64;          // wave skips tiles fully past diagonal
  const int ntw = (lim >= 0) ? ((lim >> 8) + 1) : 0;

  for (int T = 0; T < ntw; ++T) {
    // S = Q K^T (bf16x3): 4 s-frags x 4 kc x 3 = 48 MFMAs, K frags straight from L2
    vf4 sacc[4] = {vzero, vzero, vzero, vzero};
    __builtin_amdgcn_s_setprio(1);
#pragma unroll
    for (int sf = 0; sf < 4; ++sf) {
#pragma unroll
      for (int kc = 0; kc < 4; ++kc) {
        const vbf8 kh_r = *(const vbf8*)(khp + sf * 2048 + kc * 512);
        const vbf8 kl_r = *(const vbf8*)(klp + sf * 2048 + kc * 512);
        sacc[sf] = __builtin_amdgcn_mfma_f32_16x16x32_bf16(q_h[kc], kh_r, sacc[sf], 0, 0, 0);
        sacc[sf] = __builtin_amdgcn_mfma_f32_16x16x32_bf16(q_h[kc], kl_r, sacc[sf], 0, 0, 0);
        sacc[sf] = __builtin_amdgcn_mfma_f32_16x16x32_bf16(q_l[kc], kh_r, sacc[sf], 0, 0, 0);
      }
    }
    __builtin_amdgcn_s_setprio(0);

    if (T == ntw - 1) {  // causal mask (each wave's last tile is its only partial one)
#pragma unroll
      for (int sf = 0; sf < 4; ++sf) {
        const int s_g = T * 256 + sq * 64 + sf * 16 + fr;
#pragma unroll
        for (int r = 0; r < 4; ++r)
          if (s_g > q0g + fq * 4 + r) sacc[sf][r] = -__builtin_inff();
      }
    }

    // online softmax (log2 domain) over the wave's 64 s-cols (16-lane fr groups)
    float tmax[4];
#pragma unroll
    for (int r = 0; r < 4; ++r)
      tmax[r] = fmaxf(fmaxf(sacc[0][r], sacc[1][r]), fmaxf(sacc[2][r], sacc[3][r]));
#pragma unroll
    for (int off = 1; off < 16; off <<= 1)
#pragma unroll
      for (int r = 0; r < 4; ++r) tmax[r] = fmaxf(tmax[r], __shfl_xor(tmax[r], off, 64));

    // V frag loads (16) issued here; hidden under exp/psum/P-LDS below
    vbf8 vreg[8][2];
#pragma unroll
    for (int df = 0; df < 8; ++df) {
      vreg[df][0] = *(const vbf8*)(vfp + df * 32768);
      vreg[df][1] = *(const vbf8*)(vfp + df * 32768 + 512);
    }

    bool need = false;
    float mne[4];
#pragma unroll
    for (int r = 0; r < 4; ++r) {
      need |= (tmax[r] > m_r[r]);
      const float mn = fmaxf(m_r[r], tmax[r]);
      mne[r] = (mn == -__builtin_inff()) ? 0.f : mn;  // fully-masked guard
    }
    if (__any(need)) {  // rescale only when some row's max grew (exact)
#pragma unroll
      for (int r = 0; r < 4; ++r) {
        const float alpha = EXP2F(m_r[r] - mne[r]);  // m_r=-inf -> 0
        l_r[r] *= alpha;
        m_r[r] = fmaxf(m_r[r], tmax[r]);
#pragma unroll
        for (int i = 0; i < 8; ++i) oacc[i][r] *= alpha;
      }
    }

    float psum[4];
    U16 pb[4][4];
#pragma unroll
    for (int sf = 0; sf < 4; ++sf)
#pragma unroll
      for (int r = 0; r < 4; ++r) {
        const float pv = EXP2F(sacc[sf][r] - mne[r]);
        psum[r] = (sf == 0) ? pv : (psum[r] + pv);
        pb[sf][r] = f2bf(pv);
      }
#pragma unroll
    for (int off = 1; off < 16; off <<= 1)
#pragma unroll
      for (int r = 0; r < 4; ++r) psum[r] += __shfl_xor(psum[r], off, 64);
#pragma unroll
    for (int r = 0; r < 4; ++r) l_r[r] += psum[r];

    // P (C-layout) -> wave-private LDS -> two A-frags (16x64 tile)
#pragma unroll
    for (int sf = 0; sf < 4; ++sf)
#pragma unroll
      for (int r = 0; r < 4; ++r) pw[(fq * 4 + r) * 72 + sf * 16 + fr] = pb[sf][r];
    asm volatile("s_waitcnt lgkmcnt(0)" ::: "memory");
    const vbf8 pf0 = *(const vbf8*)(pw + fr * 72 + fq * 8);
    const vbf8 pf1 = *(const vbf8*)(pw + fr * 72 + 32 + fq * 8);

    // PV: 16 MFMAs from prefetched V regs
    __builtin_amdgcn_s_setprio(1);
#pragma unroll
    for (int df = 0; df < 8; ++df) {
      oacc[df] = __builtin_amdgcn_mfma_f32_16x16x32_bf16(pf0, vreg[df][0], oacc[df], 0, 0, 0);
      oacc[df] = __builtin_amdgcn_mfma_f32_16x16x32_bf16(pf1, vreg[df][1], oacc[df], 0, 0, 0);
    }
    __builtin_amdgcn_s_setprio(0);

    khp += 32768; klp += 32768; vfp += 4096;  // next 256-wide tile
  }

  // ---- 4-way s-quarter merge (only barriers in the kernel) ----
  __syncthreads();
  float* O_d = (float*)smem;                 // [3][16][128]
  float* m_s = (float*)(smem + 24576);       // [4][16]
  float* l_s = (float*)(smem + 24832);       // [4][16]
  if (sq > 0) {
#pragma unroll
    for (int i = 0; i < 8; ++i)
#pragma unroll
      for (int r = 0; r < 4; ++r)
        O_d[((sq - 1) * 16 + fq * 4 + r) * 128 + i * 16 + fr] = oacc[i][r];
  }
  if (fr == 0) {
#pragma unroll
    for (int r = 0; r < 4; ++r) {
      m_s[sq * 16 + fq * 4 + r] = m_r[r];
      l_s[sq * 16 + fq * 4 + r] = l_r[r];
    }
  }
  __syncthreads();
  if (sq == 0) {
#pragma unroll
    for (int r = 0; r < 4; ++r) {
      const int row = fq * 4 + r;
      float mv[4];
      float M = -__builtin_inff();
#pragma unroll
      for (int p = 0; p < 4; ++p) {
        mv[p] = m_s[p * 16 + row];
        M = fmaxf(M, mv[p]);
      }
      float wgt[4], denom = 0.f;
#pragma unroll
      for (int p = 0; p < 4; ++p) {
        wgt[p] = EXP2F(mv[p] - M);             // -inf (idle/masked quarter) -> 0
        denom += wgt[p] * l_s[p * 16 + row];
      }
      const float inv = 1.f / denom;           // sq0 always has the diagonal -> denom>0
#pragma unroll
      for (int i = 0; i < 8; ++i) {
        float o = wgt[0] * oacc[i][r];
#pragma unroll
        for (int p = 1; p < 4; ++p)
          o += wgt[p] * O_d[((p - 1) * 16 + row) * 128 + i * 16 + fr];
        out[(size_t)(bb * 2048 + q0g + row) * 128 + i * 16 + fr] = o * inv;
      }
    }
  }
}

// ---------------- host ----------------------------------------------------------------
extern "C" void kernel_launch(void* const* d_in, const int* in_sizes, int n_in, void* d_out,
                              int out_size, void* d_ws, size_t ws_size, hipStream_t stream) {
  const float* x = (const float*)d_in[0];
  const float* wq = (const float*)d_in[1];
  const float* wk = (const float*)d_in[2];
  const float* wv = (const float*)d_in[3];
  char* ws = (char*)d_ws;
  U16* wth = (U16*)(ws);              // 768 KB
  U16* wtl = (U16*)(ws + 786432);     // 768 KB
  U16* qfh = (U16*)(ws + 1572864);    // 4 MiB each below (fragment-major)
  U16* qfl = (U16*)(ws + 5767168);
  U16* kfh = (U16*)(ws + 9961472);
  U16* kfl = (U16*)(ws + 14155776);
  U16* vfr = (U16*)(ws + 18350080);
  float* out = (float*)d_out;

  wsplit_kernel<<<dim3(1536), dim3(256), 0, stream>>>(wq, wk, wv, wth, wtl);
  qkv_kernel<<<dim3(256, 3), dim3(256), 0, stream>>>(x, wth, wtl, qfh, qfl, kfh, kfl, vfr);
  flash_kernel<<<dim3(1024), dim3(256), 0, stream>>>(qfh, qfl, kfh, kfl, vfr, out);
}